// Round 28
// baseline (275.645 us; speedup 1.0000x reference)
//
#include <hip/hip_runtime.h>
#include <stdint.h>

// Shapes (fixed): B=512, N=128, E=128, H=4, D=512, hd=128.

typedef __attribute__((ext_vector_type(8))) __bf16 bf16x8;
typedef __attribute__((ext_vector_type(8))) uint16_t u16x8;
typedef __attribute__((ext_vector_type(4))) float f32x4;

__device__ __forceinline__ float b2f(uint16_t h) {
  union { uint32_t u; float f; } c; c.u = ((uint32_t)h) << 16; return c.f;
}
__device__ __forceinline__ uint16_t f2b(float f) {
  __bf16 h = (__bf16)f;
  union { __bf16 b; uint16_t u; } c; c.b = h; return c.u;
}
__device__ __forceinline__ void gld16(void* lds, const void* g) {
  __builtin_amdgcn_global_load_lds(
      (const __attribute__((address_space(1))) uint32_t*)(g),
      (__attribute__((address_space(3))) uint32_t*)(lds),
      16, 0, 0);
}

#define MFMA16(a, b, c) __builtin_amdgcn_mfma_f32_16x16x32_bf16((a), (b), (c), 0, 0, 0)

// ---------------- merged pack: x + all weights (out_W scaled by ln_g -> Wg2) ----------
__global__ __launch_bounds__(256) void pack_all(
    const float* __restrict__ x,
    const float* __restrict__ emb_W, const float* __restrict__ wq_W,
    const float* __restrict__ wk_W, const float* __restrict__ wv_W,
    const float* __restrict__ ipW, const float* __restrict__ out_W,
    const float* __restrict__ ln_g,
    uint16_t* __restrict__ x_bf,
    uint16_t* __restrict__ embW2, uint16_t* __restrict__ wqW_bf,
    uint16_t* __restrict__ wkW_bf, uint16_t* __restrict__ Wvc,
    uint16_t* __restrict__ ip_bf, uint16_t* __restrict__ owW_bf) {
  int i = blockIdx.x * 256 + threadIdx.x;
  if (i < 2097152) {
    float4 v = ((const float4*)x)[i];
    ushort4 o;
    o.x = f2b(v.x); o.y = f2b(v.y); o.z = f2b(v.z); o.w = f2b(v.w);
    ((ushort4*)x_bf)[i] = o;
    return;
  }
  int i2 = i - 2097152;
  if (i2 >= 360448) return;
  if (i2 >= 344064) {  // out_W scaled by ln_g -> Wg2
    const int off = i2 - 344064;
    float4 v = ((const float4*)out_W)[off];
    const int base = off * 4;
    ushort4 o;
    o.x = f2b(v.x * ln_g[(base + 0) & 511]);
    o.y = f2b(v.y * ln_g[(base + 1) & 511]);
    o.z = f2b(v.z * ln_g[(base + 2) & 511]);
    o.w = f2b(v.w * ln_g[(base + 3) & 511]);
    ((ushort4*)owW_bf)[off] = o;
    return;
  }
  const float* src; uint16_t* dst; int off;
  if (i2 < 16384)       { src = emb_W; dst = embW2;  off = i2; }
  else if (i2 < 81920)  { src = wq_W;  dst = wqW_bf; off = i2 - 16384; }
  else if (i2 < 147456) { src = wk_W;  dst = wkW_bf; off = i2 - 81920; }
  else if (i2 < 212992) { src = wv_W;  dst = Wvc;    off = i2 - 147456; }
  else                  { src = ipW;   dst = ip_bf;  off = i2 - 212992; }
  float4 v = ((const float4*)src)[off];
  ushort4 o;
  o.x = f2b(v.x); o.y = f2b(v.y); o.z = f2b(v.z); o.w = f2b(v.w);
  ((ushort4*)dst)[off] = o;
}

// ---------------- fused bias folds + zero-init (pad, stats) + emb_b copy ----------------
__global__ __launch_bounds__(256) void bias_stage1(
    const float* __restrict__ wq_W, const float* __restrict__ wk_W,
    const float* __restrict__ wv_W, const float* __restrict__ emb_b,
    const float* __restrict__ wq_b, const float* __restrict__ wk_b,
    const float* __restrict__ wv_b,
    float* __restrict__ t1q, float* __restrict__ t1k, float* __restrict__ bve,
    float* __restrict__ pad_init, float* __restrict__ biasE,
    float* __restrict__ ssum, float* __restrict__ ssq) {
  const int gid = blockIdx.x * 256 + threadIdx.x;
  if (gid < 65536) { pad_init[gid] = 0.f; ssum[gid] = 0.f; ssq[gid] = 0.f; }
  if (gid < 512) biasE[gid] = emb_b[gid];
  const int t = threadIdx.x, l = t & 63, w = t >> 6;
  const int sel = blockIdx.x >> 7;
  const int row = (blockIdx.x & 127) * 4 + w;
  const float* Wbig = sel == 0 ? wq_W : (sel == 1 ? wk_W : wv_W);
  const float* b2   = sel == 0 ? wq_b : (sel == 1 ? wk_b : wv_b);
  float* out        = sel == 0 ? t1q  : (sel == 1 ? t1k  : bve);
  float s = 0.f;
  #pragma unroll
  for (int j = 0; j < 8; ++j) {
    int c = j * 64 + l;
    s += Wbig[(size_t)row * 512 + c] * emb_b[c];
  }
  #pragma unroll
  for (int m = 1; m < 64; m <<= 1) s += __shfl_xor(s, m);
  if (l == 0) out[row] = s + b2[row];
}

__global__ __launch_bounds__(256) void bias_stage2(
    const float* __restrict__ ipW, const float* __restrict__ ipb,
    const float* __restrict__ t1q, const float* __restrict__ t1k,
    float* __restrict__ bqe, float* __restrict__ bke,
    const float* __restrict__ out_W, const float* __restrict__ ln_g,
    const float* __restrict__ ln_b, const float* __restrict__ out_b,
    float* __restrict__ u, float* __restrict__ v) {
  const int t = threadIdx.x, l = t & 63, w = t >> 6;
  const int blk = blockIdx.x;
  if (blk < 256) {
    const int sel = blk >> 7;
    const int row = (blk & 127) * 4 + w;
    const float* Wbig = ipW + (size_t)sel * 262144;
    const float* b1   = sel == 0 ? t1q : t1k;
    const float* b2   = ipb + sel * 512;
    float* out        = sel == 0 ? bqe : bke;
    float s = 0.f;
    #pragma unroll
    for (int j = 0; j < 8; ++j) {
      int c = j * 64 + l;
      s += Wbig[(size_t)row * 512 + c] * b1[c];
    }
    #pragma unroll
    for (int m = 1; m < 64; m <<= 1) s += __shfl_xor(s, m);
    if (l == 0) out[row] = s + b2[row];
  } else {
    const int r4 = (blk - 256) * 4 + w;  // 0..255
    const int row = r4 & 127;
    const float* src = (r4 < 128) ? ln_g : ln_b;
    float s = 0.f;
    #pragma unroll
    for (int j = 0; j < 8; ++j) {
      int c = j * 64 + l;
      s += out_W[(size_t)row * 512 + c] * src[c];
    }
    #pragma unroll
    for (int m = 1; m < 64; m <<= 1) s += __shfl_xor(s, m);
    if (l == 0) {
      if (r4 < 128) u[row] = s;
      else v[row] = s + out_b[row];
    }
  }
}

// ---------------- persistent-W GEMM: C(Mx512) = A(Mx128) @ W(512x128)^T + bias --------
// Zero-barrier K-loop: W panel in LDS (staged once, one sync); A fragments read
// directly from global (contiguous 16B per lane, L2-hot). 32KB LDS -> 3 blocks/CU.
// Transposed MFMA epilogue (R27): lane row=..+l15, cols=..+hi*4+r, vector stores.
template <int BIAS_MODE, bool PAD_ACC, bool HV>
__global__ __launch_bounds__(256, 3) void gemm_btp_kernel(
    const uint16_t* __restrict__ A, long long sA,
    const uint16_t* __restrict__ W, long long sW,
    const float* __restrict__ bias, long long sBias,
    uint16_t* __restrict__ C, long long sC,
    int mIter, float* __restrict__ padout,
    const uint16_t* __restrict__ xein, float* __restrict__ ssum,
    float* __restrict__ ssq) {
  __shared__ uint16_t Ws[2][128 * 64];
  const int t = threadIdx.x, l = t & 63, w = t >> 6;
  const int wr = w >> 1, wc = w & 1, l15 = l & 15, hi = l >> 4;
  const int gx = gridDim.x, gy = gridDim.y;
  const int nwg = gx * gy * gridDim.z;
  const int lin = blockIdx.x + gx * (blockIdx.y + gy * blockIdx.z);
  const int cpx = nwg >> 3;
  const int sw = (nwg & 7) ? lin : ((lin & 7) * cpx + (lin >> 3));
  const int ntile = sw % gx;
  const int rest = sw / gx;
  const int mg = rest % gy, bz = rest / gy;
  const uint16_t* Ab = A + (size_t)bz * sA;
  const uint16_t* Wb = W + (size_t)bz * sW;
  uint16_t* Cb = C + (size_t)bz * sC;
  const float* biasb = bias + (size_t)bz * sBias;
  const int srow = t >> 3;
  const int schunk = (t & 7) * 8;
  const int gchunk = (((t & 7) ^ (srow & 7)) * 8);
  const int rowB0 = ntile * 128;
  // stage W panel once (8 gld16), then a single sync; K-loop has NO barriers.
  #pragma unroll
  for (int kt = 0; kt < 2; ++kt)
    #pragma unroll
    for (int i = 0; i < 4; ++i) {
      const int r = i * 32 + srow;
      gld16(&Ws[kt][r * 64 + schunk], Wb + (size_t)(rowB0 + r) * 128 + kt * 64 + gchunk);
    }
  asm volatile("s_waitcnt vmcnt(0)" ::: "memory");
  __syncthreads();
  const int rsw = (l15 & 7);
  for (int it = 0; it < mIter; ++it) {
    const int rowA0 = (mg * mIter + it) * 128;
    f32x4 acc[4][4];
    #pragma unroll
    for (int m = 0; m < 4; ++m)
      #pragma unroll
      for (int n = 0; n < 4; ++n) acc[m][n] = (f32x4){0.f, 0.f, 0.f, 0.f};
    #pragma unroll
    for (int kt = 0; kt < 2; ++kt)
      #pragma unroll
      for (int ks = 0; ks < 2; ++ks) {
        const int gck = ((ks * 4 + hi) ^ rsw) * 8;
        bf16x8 bb[4];
        #pragma unroll
        for (int n = 0; n < 4; ++n)
          bb[n] = *(const bf16x8*)&Ws[kt][(wc * 64 + n * 16 + l15) * 64 + gck];
        #pragma unroll
        for (int m = 0; m < 4; ++m) {
          // A fragment direct from global: contiguous 16B, no swizzle needed
          bf16x8 a = *(const bf16x8*)(Ab +
              (size_t)(rowA0 + wr * 64 + m * 16 + l15) * 128 +
              kt * 64 + (ks * 4 + hi) * 8);
          #pragma unroll
          for (int n = 0; n < 4; ++n) acc[m][n] = MFMA16(bb[n], a, acc[m][n]);
        }
      }
    // transposed-fragment epilogue: lane row = ..+l15, cols = ..+hi*4+r
    #pragma unroll
    for (int m = 0; m < 4; ++m) {
      const int row = rowA0 + wr * 64 + m * 16 + l15;
      float padp = 0.f, hs = 0.f, hq = 0.f;
      #pragma unroll
      for (int n = 0; n < 4; ++n) {
        const int colb = rowB0 + wc * 64 + n * 16 + hi * 4;
        union { ushort4 v; uint16_t e[4]; } o, xv;
        if constexpr (HV)
          xv.v = *(const ushort4*)&xein[(size_t)row * 512 + colb];
        #pragma unroll
        for (int r = 0; r < 4; ++r) {
          float rv = acc[m][n][r];
          if constexpr (BIAS_MODE == 1) rv += biasb[colb + r];
          if constexpr (PAD_ACC) padp += fabsf(rv);
          if constexpr (HV) {
            const float sp = fmaxf(rv, 0.f) + __logf(1.f + __expf(-fabsf(rv)));
            const float hvv = b2f(xv.e[r]) + sp;
            hs += hvv;
            hq += hvv * hvv;
            o.e[r] = f2b(hvv);
          } else {
            o.e[r] = f2b(rv);
          }
        }
        *(ushort4*)&Cb[(size_t)row * 512 + colb] = o.v;
      }
      if constexpr (PAD_ACC) {
        if (bz == 0) {
          padp += __shfl_xor(padp, 16);
          padp += __shfl_xor(padp, 32);
          if (l < 16) atomicAdd(padout + row, padp);
        }
      }
      if constexpr (HV) {
        hs += __shfl_xor(hs, 16); hs += __shfl_xor(hs, 32);
        hq += __shfl_xor(hq, 16); hq += __shfl_xor(hq, 32);
        if (l < 16) {
          atomicAdd(ssum + row, hs);
          atomicAdd(ssq + row, hq);
        }
      }
    }
  }
}

// ---------------- generic C(MxN) = A(MxK) @ W(NxK)^T (final GEMM; LN fold) ----
// Transposed fragment epilogue: row = ..+l15 (mu/rstd once per m), float4 stores.
template <typename OT, int BIAS_MODE, bool LN>
__global__ __launch_bounds__(256) void gemm_bt_kernel(
    const uint16_t* __restrict__ A, long long sA,
    const uint16_t* __restrict__ W, long long sW,
    const float* __restrict__ bias, long long sBias,
    OT* __restrict__ C, long long sC, int N, int K,
    const float* __restrict__ ssum, const float* __restrict__ ssq,
    const float* __restrict__ uarr, const float* __restrict__ varr) {
  __shared__ uint16_t As[2][128 * 64];
  __shared__ uint16_t Bs[2][128 * 64];
  const int t = threadIdx.x, l = t & 63, w = t >> 6;
  const int wr = w >> 1, wc = w & 1, l15 = l & 15, hi = l >> 4;
  const int gx = gridDim.x, gy = gridDim.y;
  const int nwg = gx * gy * gridDim.z;
  const int lin = blockIdx.x + gx * (blockIdx.y + gy * blockIdx.z);
  const int cpx = nwg >> 3;
  const int sw = (nwg & 7) ? lin : ((lin & 7) * cpx + (lin >> 3));
  const int ntile = sw % gx;
  const int rest = sw / gx;
  const int mtile = rest % gy, bz = rest / gy;
  const uint16_t* Ab = A + (size_t)bz * sA;
  const uint16_t* Wb = W + (size_t)bz * sW;
  OT* Cb = C + (size_t)bz * sC;
  const float* biasb = bias + (size_t)bz * sBias;
  f32x4 acc[4][4];
  #pragma unroll
  for (int m = 0; m < 4; ++m)
    #pragma unroll
    for (int n = 0; n < 4; ++n) acc[m][n] = (f32x4){0.f, 0.f, 0.f, 0.f};
  const int srow = t >> 3;
  const int schunk = (t & 7) * 8;
  const int gchunk = (((t & 7) ^ (srow & 7)) * 8);
  const int nk = K >> 6;
  const int rowA0 = mtile * 128, rowB0 = ntile * 128;
  auto stage = [&](int kt, int buf) {
    const int kb = kt << 6;
    #pragma unroll
    for (int i = 0; i < 4; ++i) {
      const int r = i * 32 + srow;
      gld16(&As[buf][r * 64 + schunk], Ab + (size_t)(rowA0 + r) * K + kb + gchunk);
      gld16(&Bs[buf][r * 64 + schunk], Wb + (size_t)(rowB0 + r) * K + kb + gchunk);
    }
  };
  stage(0, 0);
  const int rsw = (l15 & 7);
  for (int kt = 0; kt < nk; ++kt) {
    const int cur = kt & 1;
    if (kt + 1 < nk) {
      stage(kt + 1, cur ^ 1);
      asm volatile("s_waitcnt vmcnt(8)" ::: "memory");
    } else {
      asm volatile("s_waitcnt vmcnt(0)" ::: "memory");
    }
    __builtin_amdgcn_s_barrier();
    asm volatile("" ::: "memory");
    #pragma unroll
    for (int ks = 0; ks < 2; ++ks) {
      const int gck = ((ks * 4 + hi) ^ rsw) * 8;
      bf16x8 a[4], bb[4];
      #pragma unroll
      for (int m = 0; m < 4; ++m)
        a[m] = *(const bf16x8*)&As[cur][(wr * 64 + m * 16 + l15) * 64 + gck];
      #pragma unroll
      for (int n = 0; n < 4; ++n)
        bb[n] = *(const bf16x8*)&Bs[cur][(wc * 64 + n * 16 + l15) * 64 + gck];
      // swapped operands -> transposed fragment
      #pragma unroll
      for (int m = 0; m < 4; ++m)
        #pragma unroll
        for (int n = 0; n < 4; ++n) acc[m][n] = MFMA16(bb[n], a[m], acc[m][n]);
    }
    asm volatile("" ::: "memory");
    __builtin_amdgcn_s_barrier();
  }
  #pragma unroll
  for (int m = 0; m < 4; ++m) {
    const int row = rowA0 + wr * 64 + m * 16 + l15;
    float mu = 0.f, rstd = 0.f;
    if constexpr (LN) {
      mu = ssum[row] * (1.f / 512.f);
      const float var = ssq[row] * (1.f / 512.f) - mu * mu;
      rstd = rsqrtf(var + 1e-5f);
    }
    #pragma unroll
    for (int n = 0; n < 4; ++n) {
      const int colb = rowB0 + wc * 64 + n * 16 + hi * 4;
      if constexpr (sizeof(OT) == 2) {
        union { ushort4 v; uint16_t e[4]; } o;
        #pragma unroll
        for (int r = 0; r < 4; ++r) {
          float rv;
          if constexpr (LN) {
            rv = rstd * (acc[m][n][r] - mu * uarr[colb + r]) + varr[colb + r];
          } else {
            float bv = 0.f;
            if constexpr (BIAS_MODE == 1) bv = biasb[colb + r];
            rv = acc[m][n][r] + bv;
          }
          o.e[r] = f2b(rv);
        }
        *(ushort4*)&((uint16_t*)Cb)[(size_t)row * N + colb] = o.v;
      } else {
        union { float4 v; float e[4]; } o;
        #pragma unroll
        for (int r = 0; r < 4; ++r) {
          float rv;
          if constexpr (LN) {
            rv = rstd * (acc[m][n][r] - mu * uarr[colb + r]) + varr[colb + r];
          } else {
            float bv = 0.f;
            if constexpr (BIAS_MODE == 1) bv = biasb[colb + r];
            rv = acc[m][n][r] + bv;
          }
          o.e[r] = rv;
        }
        *(float4*)&Cb[(size_t)row * N + colb] = o.v;
      }
    }
  }
}

// ---------------- C = A(MxK) @ B(KxN), B row-major (weight prep only) ----
__global__ __launch_bounds__(256) void gemm_ab_kernel(
    const uint16_t* __restrict__ A, int lda, long long sA,
    const uint16_t* __restrict__ B, int ldb, long long sB,
    uint16_t* __restrict__ C, int ldc, long long sC, int K) {
  __shared__ uint16_t As[128 * 64];
  __shared__ uint16_t Bt[128 * 64];
  const int t = threadIdx.x, l = t & 63, w = t >> 6;
  const int wr = w >> 1, wc = w & 1, l15 = l & 15, hi = l >> 4;
  const int gx = gridDim.x, gy = gridDim.y;
  const int nwg = gx * gy * gridDim.z;
  const int lin = blockIdx.x + gx * (blockIdx.y + gy * blockIdx.z);
  const int cpx = nwg >> 3;
  const int sw = (nwg & 7) ? lin : ((lin & 7) * cpx + (lin >> 3));
  const int ntile = sw % gx;
  const int rest = sw / gx;
  const int mtile = rest % gy, bz = rest / gy;
  const uint16_t* Ab = A + (size_t)bz * sA;
  const uint16_t* Bb = B + (size_t)bz * sB;
  uint16_t* Cb = C + (size_t)bz * sC;
  f32x4 acc[4][4];
  #pragma unroll
  for (int m = 0; m < 4; ++m)
    #pragma unroll
    for (int n = 0; n < 4; ++n) acc[m][n] = (f32x4){0.f, 0.f, 0.f, 0.f};
  const int srow = t >> 3, schunk = (t & 7) * 8;
  const int nk = K >> 6;
  for (int kt = 0; kt < nk; ++kt) {
    const int kb = kt << 6;
    #pragma unroll
    for (int i = 0; i < 4; ++i) {
      const int r = i * 32 + srow;
      gld16(&As[r * 64 + schunk], Ab + (size_t)(mtile * 128 + r) * lda + kb + schunk);
    }
    #pragma unroll
    for (int rd = 0; rd < 4; ++rd) {
      const int id = rd * 256 + t;
      const int kr = id >> 4;
      const int c = (id & 15) * 8;
      u16x8 gv = *(const u16x8*)(Bb + (size_t)(kb + kr) * ldb + ntile * 128 + c);
      #pragma unroll
      for (int j = 0; j < 8; ++j) Bt[(c + j) * 64 + kr] = gv[j];
    }
    __syncthreads();
    #pragma unroll
    for (int ks = 0; ks < 2; ++ks) {
      const int k0 = ks * 32 + hi * 8;
      bf16x8 a[4], bb[4];
      #pragma unroll
      for (int m = 0; m < 4; ++m) a[m] = *(const bf16x8*)&As[(wr * 64 + m * 16 + l15) * 64 + k0];
      #pragma unroll
      for (int n = 0; n < 4; ++n) bb[n] = *(const bf16x8*)&Bt[(wc * 64 + n * 16 + l15) * 64 + k0];
      #pragma unroll
      for (int m = 0; m < 4; ++m)
        #pragma unroll
        for (int n = 0; n < 4; ++n) acc[m][n] = MFMA16(a[m], bb[n], acc[m][n]);
    }
    __syncthreads();
  }
  #pragma unroll
  for (int m = 0; m < 4; ++m) {
    const int row = mtile * 128 + wr * 64 + m * 16 + hi * 4;
    #pragma unroll
    for (int n = 0; n < 4; ++n) {
      const int col = ntile * 128 + wc * 64 + n * 16 + l15;
      #pragma unroll
      for (int r = 0; r < 4; ++r)
        Cb[(size_t)(row + r) * ldc + col] = f2b(acc[m][n][r]);
    }
  }
}

// ---------------- Wg_h[e][d] = sum_o Wke_h[o][e]*Wqe_h[o][d] ; v_h[e] = sum_o Wke_h[o][e]*bqe_h[o]
__global__ __launch_bounds__(256) void gemm_atb_kernel(
    const uint16_t* __restrict__ Wke, const uint16_t* __restrict__ Wqe,
    const float* __restrict__ bqe, uint16_t* __restrict__ Wg,
    float* __restrict__ vh) {
  __shared__ uint16_t At[128 * 64];
  __shared__ uint16_t Bt[128 * 64];
  const int h = blockIdx.x;
  const int t = threadIdx.x, l = t & 63, w = t >> 6;
  const int wr = w >> 1, wc = w & 1, l15 = l & 15, hi = l >> 4;
  const uint16_t* A = Wke + (size_t)h * 16384;
  const uint16_t* B = Wqe + (size_t)h * 16384;
  f32x4 acc[4][4];
  #pragma unroll
  for (int m = 0; m < 4; ++m)
    #pragma unroll
    for (int n = 0; n < 4; ++n) acc[m][n] = (f32x4){0.f, 0.f, 0.f, 0.f};
  float vacc = 0.f;
  for (int kt = 0; kt < 2; ++kt) {
    const int kb = kt << 6;
    #pragma unroll
    for (int rd = 0; rd < 4; ++rd) {
      const int id = rd * 256 + t;
      const int kr = id >> 4;
      const int c = (id & 15) * 8;
      u16x8 ga = *(const u16x8*)(A + (size_t)(kb + kr) * 128 + c);
      u16x8 gb = *(const u16x8*)(B + (size_t)(kb + kr) * 128 + c);
      #pragma unroll
      for (int j = 0; j < 8; ++j) {
        const int row = c + j;
        const int sxz = (((row & 7) ^ ((row >> 3) & 7)) << 3);
        At[row * 64 + (kr ^ sxz)] = ga[j];
        Bt[row * 64 + (kr ^ sxz)] = gb[j];
      }
    }
    __syncthreads();
    if (t < 128) {
      const int sxz = (((t & 7) ^ ((t >> 3) & 7)) << 3);
      for (int o = 0; o < 64; ++o)
        vacc += b2f(At[t * 64 + (o ^ sxz)]) * bqe[h * 128 + kb + o];
    }
    #pragma unroll
    for (int ks = 0; ks < 2; ++ks) {
      bf16x8 a[4], bb[4];
      #pragma unroll
      for (int m = 0; m < 4; ++m) {
        const int mr = wr * 64 + m * 16 + l15;
        const int sxz = (((mr & 7) ^ ((mr >> 3) & 7)) << 3);
        a[m] = *(const bf16x8*)&At[mr * 64 + ((ks * 32 + hi * 8) ^ sxz)];
      }
      #pragma unroll
      for (int n = 0; n < 4; ++n) {
        const int nr = wc * 64 + n * 16 + l15;
        const int sxz = (((nr & 7) ^ ((nr >> 3) & 7)) << 3);
        bb[n] = *(const bf16x8*)&Bt[nr * 64 + ((ks * 32 + hi * 8) ^ sxz)];
      }
      #pragma unroll
      for (int m = 0; m < 4; ++m)
        #pragma unroll
        for (int n = 0; n < 4; ++n) acc[m][n] = MFMA16(a[m], bb[n], acc[m][n]);
    }
    __syncthreads();
  }
  if (t < 128) vh[h * 128 + t] = vacc;
  #pragma unroll
  for (int m = 0; m < 4; ++m) {
    const int row = wr * 64 + m * 16 + hi * 4;
    #pragma unroll
    for (int n = 0; n < 4; ++n) {
      const int col = wc * 64 + n * 16 + l15;
      #pragma unroll
      for (int r = 0; r < 4; ++r)
        Wg[(size_t)h * 16384 + (size_t)(row + r) * 128 + col] = f2b(acc[m][n][r]);
    }
  }
}

// ---------------- fused attention + PV (512 threads / 8 waves) ----------------------
__global__ __launch_bounds__(512) void att_fused(
    const uint16_t* __restrict__ xg, const uint16_t* __restrict__ Wg,
    const float* __restrict__ vh, const float* __restrict__ wts,
    const float* __restrict__ padsum, uint16_t* __restrict__ tout) {
  __shared__ uint16_t Xr[2][128 * 64];
  __shared__ uint16_t GP[2][128 * 64];
  __shared__ float bS[4][128];
  const int blk = blockIdx.x;
  const int b = (blk & 7) * 64 + (blk >> 3);
  const int t = threadIdx.x, l = t & 63, wband = t >> 6;
  const int l15 = l & 15, hi = l >> 4;
  const int srow = t >> 3;
  const int schunk = (t & 7) * 8;
  const int gchunk = (((t & 7) ^ (srow & 7)) * 8);
  const float SCALE = 0.088388347648318447f;
  const int rsw = (l15 & 7);

  const uint16_t* xb = xg + (size_t)b * 16384;
  #pragma unroll
  for (int kt = 0; kt < 2; ++kt)
    #pragma unroll
    for (int i = 0; i < 2; ++i) {
      const int r = i * 64 + srow;
      gld16(&Xr[kt][r * 64 + schunk], xb + (size_t)r * 128 + kt * 64 + gchunk);
      gld16(&GP[kt][r * 64 + schunk], Wg + (size_t)r * 128 + kt * 64 + gchunk);
    }
  asm volatile("s_waitcnt vmcnt(0)" ::: "memory");
  __builtin_amdgcn_s_barrier();
  {
    const int hh = t >> 7, j = t & 127;
    float s = 0.f;
    for (int e = 0; e < 128; ++e) {
      const int c = e & 63;
      const int addr = j * 64 + ((((c >> 3) ^ (j & 7)) << 3) | (c & 7));
      s += b2f(Xr[e >> 6][addr]) * vh[hh * 128 + e];
    }
    bS[hh][j] = s * SCALE +
                ((padsum[(size_t)b * 128 + j] == 0.f) ? -__builtin_inff() : 0.f);
  }

  f32x4 awacc[8];
  #pragma unroll
  for (int n = 0; n < 8; ++n) awacc[n] = (f32x4){0.f, 0.f, 0.f, 0.f};
  u16x8 wreg[4];
  u16x8 xtr[4];

  for (int h = 0; h < 4; ++h) {
    f32x4 pacc[8];
    #pragma unroll
    for (int n = 0; n < 8; ++n) pacc[n] = (f32x4){0.f, 0.f, 0.f, 0.f};
    __builtin_amdgcn_s_setprio(1);
    #pragma unroll
    for (int kt = 0; kt < 2; ++kt)
      #pragma unroll
      for (int ks = 0; ks < 2; ++ks) {
        const int gck = ((ks * 4 + hi) ^ rsw) * 8;
        bf16x8 a, bb[8];
        a = *(const bf16x8*)&Xr[kt][(wband * 16 + l15) * 64 + gck];
        #pragma unroll
        for (int n = 0; n < 8; ++n)
          bb[n] = *(const bf16x8*)&GP[kt][(n * 16 + l15) * 64 + gck];
        #pragma unroll
        for (int n = 0; n < 8; ++n) pacc[n] = MFMA16(a, bb[n], pacc[n]);
      }
    __builtin_amdgcn_s_setprio(0);
    if (h + 1 < 4) {
      #pragma unroll
      for (int kt = 0; kt < 2; ++kt)
        #pragma unroll
        for (int i = 0; i < 2; ++i) {
          const int r = i * 64 + srow;
          wreg[kt * 2 + i] = *(const u16x8*)(Wg + (size_t)(h + 1) * 16384 +
                                             (size_t)r * 128 + kt * 64 + gchunk);
        }
    }
    __builtin_amdgcn_s_barrier();
    #pragma unroll
    for (int n = 0; n < 8; ++n) {
      const int cl = n * 16 + l15;
      const int c = cl & 63;
      #pragma unroll
      for (int r = 0; r < 4; ++r) {
        const int rr = wband * 16 + hi * 4 + r;
        GP[cl >> 6][rr * 64 + ((((c >> 3) ^ (rr & 7)) << 3) | (c & 7))] =
            f2b(pacc[n][r]);
      }
    }
    __builtin_amdgcn_s_barrier();
    f32x4 sacc[8];
    #pragma unroll
    for (int n = 0; n < 8; ++n) sacc[n] = (f32x4){0.f, 0.f, 0.f, 0.f};
    __builtin_amdgcn_s_setprio(1);
    #pragma unroll
    for (int kt = 0; kt < 2; ++kt)
      #pragma unroll
      for (int ks = 0; ks < 2; ++ks) {
        const int gck = ((ks * 4 + hi) ^ rsw) * 8;
        bf16x8 a, bb[8];
        a = *(const bf16x8*)&GP[kt][(wband * 16 + l15) * 64 + gck];
        #pragma unroll
        for (int n = 0; n < 8; ++n)
          bb[n] = *(const bf16x8*)&Xr[kt][(n * 16 + l15) * 64 + gck];
        #pragma unroll
        for (int n = 0; n < 8; ++n) sacc[n] = MFMA16(a, bb[n], sacc[n]);
      }
    __builtin_amdgcn_s_setprio(0);
    if (h == 3) {
      #pragma unroll
      for (int i = 0; i < 4; ++i) {
        const int id = i * 512 + t;
        const int jr = id >> 4;
        const int cc = (id & 15) * 8;
        xtr[i] = *(const u16x8*)(xb + (size_t)jr * 128 + cc);
      }
    }
    #pragma unroll
    for (int r = 0; r < 4; ++r) {
      float e[8], z = 0.f;
      #pragma unroll
      for (int n = 0; n < 8; ++n) {
        e[n] = __expf(sacc[n][r] * SCALE + bS[h][n * 16 + l15]);
        z += e[n];
      }
      z += __shfl_xor(z, 1); z += __shfl_xor(z, 2);
      z += __shfl_xor(z, 4); z += __shfl_xor(z, 8);
      const float zi = 1.f / z;
      #pragma unroll
      for (int n = 0; n < 8; ++n) awacc[n][r] += e[n] * zi;
    }
    if (h + 1 < 4) {
      __builtin_amdgcn_s_barrier();
      asm volatile("s_waitcnt vmcnt(0)" ::: "memory");
      #pragma unroll
      for (int kt = 0; kt < 2; ++kt)
        #pragma unroll
        for (int i = 0; i < 2; ++i) {
          const int r = i * 64 + srow;
          *(u16x8*)&GP[kt][r * 64 + schunk] = wreg[kt * 2 + i];
        }
      __builtin_amdgcn_s_barrier();
    }
  }
  float wv[8];
  #pragma unroll
  for (int n = 0; n < 8; ++n) wv[n] = wts[(size_t)b * 128 + n * 16 + l15];
  __builtin_amdgcn_s_barrier();
  #pragma unroll
  for (int r = 0; r < 4; ++r) {
    float z = 0.f;
    #pragma unroll
    for (int n = 0; n < 8; ++n) z += awacc[n][r] * wv[n];
    z += __shfl_xor(z, 1); z += __shfl_xor(z, 2);
    z += __shfl_xor(z, 4); z += __shfl_xor(z, 8);
    const float zi = 1.f / z;
    const int rr = wband * 16 + hi * 4 + r;
    #pragma unroll
    for (int n = 0; n < 8; ++n) {
      const int cl = n * 16 + l15;
      const int c = cl & 63;
      GP[cl >> 6][rr * 64 + ((((c >> 3) ^ (rr & 7)) << 3) | (c & 7))] =
          f2b(awacc[n][r] * wv[n] * zi);
    }
  }
  asm volatile("s_waitcnt vmcnt(0)" ::: "memory");
  #pragma unroll
  for (int i = 0; i < 4; ++i) {
    const int id = i * 512 + t;
    const int jr = id >> 4;
    const int cc = (id & 15) * 8;
    const int kt2 = jr >> 6, kr = jr & 63;
    #pragma unroll
    for (int j = 0; j < 8; ++j) {
      const int drow = cc + j;
      const int sxz = (((drow & 7) ^ ((drow >> 3) & 7)) << 3);
      Xr[kt2][drow * 64 + (kr ^ sxz)] = xtr[i][j];
    }
  }
  __builtin_amdgcn_s_barrier();
  f32x4 tacc[8];
  #pragma unroll
  for (int n = 0; n < 8; ++n) tacc[n] = (f32x4){0.f, 0.f, 0.f, 0.f};
  __builtin_amdgcn_s_setprio(1);
  #pragma unroll
  for (int kt = 0; kt < 2; ++kt)
    #pragma unroll
    for (int ks = 0; ks < 2; ++ks) {
      const int gck = ((ks * 4 + hi) ^ rsw) * 8;
      bf16x8 a, bb[8];
      a = *(const bf16x8*)&GP[kt][(wband * 16 + l15) * 64 + gck];
      #pragma unroll
      for (int n = 0; n < 8; ++n) {
        const int nr = n * 16 + l15;
        const int sxz = (((nr & 7) ^ ((nr >> 3) & 7)) << 3);
        bb[n] = *(const bf16x8*)&Xr[kt][nr * 64 + ((ks * 32 + hi * 8) ^ sxz)];
      }
      #pragma unroll
      for (int n = 0; n < 8; ++n) tacc[n] = MFMA16(a, bb[n], tacc[n]);
    }
  __builtin_amdgcn_s_setprio(0);
  #pragma unroll
  for (int r = 0; r < 4; ++r) {
    const int row = wband * 16 + hi * 4 + r;
    #pragma unroll
    for (int n = 0; n < 8; ++n) {
      const int col = n * 16 + l15;
      tout[(size_t)b * 16384 + (size_t)row * 128 + col] = f2b(tacc[n][r]);
    }
  }
}

// =======================================================================================
extern "C" void kernel_launch(void* const* d_in, const int* in_sizes, int n_in,
                              void* d_out, int out_size, void* d_ws, size_t ws_size,
                              hipStream_t stream) {
  (void)in_sizes; (void)n_in; (void)out_size; (void)ws_size;
  const float* x     = (const float*)d_in[0];
  const float* wts   = (const float*)d_in[1];
  const float* emb_W = (const float*)d_in[2];
  const float* emb_b = (const float*)d_in[3];
  const float* wq_W  = (const float*)d_in[4];
  const float* wq_b  = (const float*)d_in[5];
  const float* wk_W  = (const float*)d_in[6];
  const float* wk_b  = (const float*)d_in[7];
  const float* wv_W  = (const float*)d_in[8];
  const float* wv_b  = (const float*)d_in[9];
  const float* ipW   = (const float*)d_in[10];
  const float* ipb   = (const float*)d_in[11];
  const float* ln_g  = (const float*)d_in[12];
  const float* ln_b  = (const float*)d_in[13];
  const float* out_W = (const float*)d_in[14];
  const float* out_b = (const float*)d_in[15];

  char* ws = (char*)d_ws;
  size_t off = 0;
  auto alloc = [&](size_t bytes) { void* p = ws + off; off += (bytes + 255) & ~(size_t)255; return p; };
  uint16_t* wqW_bf = (uint16_t*)alloc(524288);
  uint16_t* wkW_bf = (uint16_t*)alloc(524288);
  uint16_t* ip_bf  = (uint16_t*)alloc(1048576);
  uint16_t* owW_bf = (uint16_t*)alloc(131072);     // Wg2 = out_W * ln_g
  uint16_t* Wqc    = (uint16_t*)alloc(524288);     // contiguous Wqc,Wkc,Wvc
  uint16_t* Wkc    = (uint16_t*)alloc(524288);
  uint16_t* Wvc    = (uint16_t*)alloc(524288);
  uint16_t* embW2  = (uint16_t*)alloc(131072);     // contiguous embW2,Wqe,Wke,Wve
  uint16_t* Wqe    = (uint16_t*)alloc(131072);
  uint16_t* Wke    = (uint16_t*)alloc(131072);
  uint16_t* Wve    = (uint16_t*)alloc(131072);
  uint16_t* Wg     = (uint16_t*)alloc(131072);
  float*    vhbuf  = (float*)alloc(2048);
  float*    t1q    = (float*)alloc(2048);
  float*    t1k    = (float*)alloc(2048);
  float*    biasE  = (float*)alloc(2048);
  float*    bqe    = (float*)alloc(2048);
  float*    bke    = (float*)alloc(2048);
  float*    bve    = (float*)alloc(2048);
  float*    uarr   = (float*)alloc(2048);
  float*    varr   = (float*)alloc(2048);
  float*    pad    = (float*)alloc(262144);
  float*    ssum   = (float*)alloc(262144);
  float*    ssq    = (float*)alloc(262144);
  uint16_t* xe     = (uint16_t*)alloc(67108864);
  uint16_t* B1     = (uint16_t*)alloc(67108864);   // t
  uint16_t* B2     = (uint16_t*)alloc(67108864);   // hv

  uint16_t* x_bf = (uint16_t*)d_out + 8388608;     // d_out upper 16 MiB
  uint16_t* tb   = B1;
  uint16_t* hv   = B2;

  const int TB = 256;
  pack_all<<<9600, TB, 0, stream>>>(x, emb_W, wq_W, wk_W, wv_W, ipW, out_W, ln_g,
                                    x_bf, embW2, wqW_bf, wkW_bf, Wvc, ip_bf, owW_bf);
  bias_stage1<<<384, TB, 0, stream>>>(wq_W, wk_W, wv_W, emb_b, wq_b, wk_b, wv_b,
                                      t1q, t1k, bve, pad, biasE, ssum, ssq);
  bias_stage2<<<320, TB, 0, stream>>>(ipW, ipb, t1q, t1k, bqe, bke,
                                      out_W, ln_g, ln_b, out_b, uarr, varr);
  gemm_ab_kernel<<<dim3(4, 4, 2), TB, 0, stream>>>(ip_bf, 512, 262144, wqW_bf, 512, 262144,
                                                   Wqc, 512, 262144, 512);
  gemm_ab_kernel<<<dim3(1, 4, 3), TB, 0, stream>>>(Wqc, 512, 262144, embW2, 128, 0,
                                                   Wqe, 128, 65536, 512);
  gemm_atb_kernel<<<4, TB, 0, stream>>>(Wke, Wqe, bqe, Wg, vhbuf);
  // xe = x @ emb_W^T + emb_b (persistent W in LDS; A direct from global; no barriers)
  gemm_btp_kernel<1, true, false><<<dim3(4, 128, 1), TB, 0, stream>>>(
      x_bf, 0, embW2, 0, biasE, 0, xe, 0, 4, pad, nullptr, nullptr, nullptr);
  // fused attention + PV -> t
  att_fused<<<512, 512, 0, stream>>>(x_bf, Wg, vhbuf, wts, pad, tb);
  // hv = xe + softplus(t @ Wve^T + bve); row stats accumulated via atomics
  gemm_btp_kernel<1, false, true><<<dim3(4, 128, 1), TB, 0, stream>>>(
      tb, 0, Wve, 0, bve, 0, hv, 0, 4, nullptr, xe, ssum, ssq);
  // out = LN-fold: rstd*(hv@Wg2^T - mu*u) + v, f32 -> d_out
  gemm_bt_kernel<float, 0, true><<<dim3(1, 512, 1), TB, 0, stream>>>(
      hv, 0, owW_bf, 0, nullptr, 0, (float*)d_out, 0, 128, 512,
      ssum, ssq, uarr, varr);
}

// Round 29
// 221.789 us; speedup vs baseline: 1.2428x; 1.2428x over previous
//
#include <hip/hip_runtime.h>
#include <stdint.h>

// Shapes (fixed): B=512, N=128, E=128, H=4, D=512, hd=128.

typedef __attribute__((ext_vector_type(8))) __bf16 bf16x8;
typedef __attribute__((ext_vector_type(8))) uint16_t u16x8;
typedef __attribute__((ext_vector_type(4))) float f32x4;

__device__ __forceinline__ float b2f(uint16_t h) {
  union { uint32_t u; float f; } c; c.u = ((uint32_t)h) << 16; return c.f;
}
__device__ __forceinline__ uint16_t f2b(float f) {
  __bf16 h = (__bf16)f;
  union { __bf16 b; uint16_t u; } c; c.b = h; return c.u;
}
__device__ __forceinline__ void gld16(void* lds, const void* g) {
  __builtin_amdgcn_global_load_lds(
      (const __attribute__((address_space(1))) uint32_t*)(g),
      (__attribute__((address_space(3))) uint32_t*)(lds),
      16, 0, 0);
}

#define MFMA16(a, b, c) __builtin_amdgcn_mfma_f32_16x16x32_bf16((a), (b), (c), 0, 0, 0)

// ---------------- merged pack: x + all weights (out_W scaled by ln_g -> Wg2) ----------
__global__ __launch_bounds__(256) void pack_all(
    const float* __restrict__ x,
    const float* __restrict__ emb_W, const float* __restrict__ wq_W,
    const float* __restrict__ wk_W, const float* __restrict__ wv_W,
    const float* __restrict__ ipW, const float* __restrict__ out_W,
    const float* __restrict__ ln_g,
    uint16_t* __restrict__ x_bf,
    uint16_t* __restrict__ embW2, uint16_t* __restrict__ wqW_bf,
    uint16_t* __restrict__ wkW_bf, uint16_t* __restrict__ Wvc,
    uint16_t* __restrict__ ip_bf, uint16_t* __restrict__ owW_bf) {
  int i = blockIdx.x * 256 + threadIdx.x;
  if (i < 2097152) {
    float4 v = ((const float4*)x)[i];
    ushort4 o;
    o.x = f2b(v.x); o.y = f2b(v.y); o.z = f2b(v.z); o.w = f2b(v.w);
    ((ushort4*)x_bf)[i] = o;
    return;
  }
  int i2 = i - 2097152;
  if (i2 >= 360448) return;
  if (i2 >= 344064) {  // out_W scaled by ln_g -> Wg2
    const int off = i2 - 344064;
    float4 v = ((const float4*)out_W)[off];
    const int base = off * 4;
    ushort4 o;
    o.x = f2b(v.x * ln_g[(base + 0) & 511]);
    o.y = f2b(v.y * ln_g[(base + 1) & 511]);
    o.z = f2b(v.z * ln_g[(base + 2) & 511]);
    o.w = f2b(v.w * ln_g[(base + 3) & 511]);
    ((ushort4*)owW_bf)[off] = o;
    return;
  }
  const float* src; uint16_t* dst; int off;
  if (i2 < 16384)       { src = emb_W; dst = embW2;  off = i2; }
  else if (i2 < 81920)  { src = wq_W;  dst = wqW_bf; off = i2 - 16384; }
  else if (i2 < 147456) { src = wk_W;  dst = wkW_bf; off = i2 - 81920; }
  else if (i2 < 212992) { src = wv_W;  dst = Wvc;    off = i2 - 147456; }
  else                  { src = ipW;   dst = ip_bf;  off = i2 - 212992; }
  float4 v = ((const float4*)src)[off];
  ushort4 o;
  o.x = f2b(v.x); o.y = f2b(v.y); o.z = f2b(v.z); o.w = f2b(v.w);
  ((ushort4*)dst)[off] = o;
}

// ---------------- fused bias folds + zero-init (pad, stats) + emb_b copy ----------------
__global__ __launch_bounds__(256) void bias_stage1(
    const float* __restrict__ wq_W, const float* __restrict__ wk_W,
    const float* __restrict__ wv_W, const float* __restrict__ emb_b,
    const float* __restrict__ wq_b, const float* __restrict__ wk_b,
    const float* __restrict__ wv_b,
    float* __restrict__ t1q, float* __restrict__ t1k, float* __restrict__ bve,
    float* __restrict__ pad_init, float* __restrict__ biasE,
    float* __restrict__ ssum, float* __restrict__ ssq) {
  const int gid = blockIdx.x * 256 + threadIdx.x;
  if (gid < 65536) { pad_init[gid] = 0.f; ssum[gid] = 0.f; ssq[gid] = 0.f; }
  if (gid < 512) biasE[gid] = emb_b[gid];
  const int t = threadIdx.x, l = t & 63, w = t >> 6;
  const int sel = blockIdx.x >> 7;
  const int row = (blockIdx.x & 127) * 4 + w;
  const float* Wbig = sel == 0 ? wq_W : (sel == 1 ? wk_W : wv_W);
  const float* b2   = sel == 0 ? wq_b : (sel == 1 ? wk_b : wv_b);
  float* out        = sel == 0 ? t1q  : (sel == 1 ? t1k  : bve);
  float s = 0.f;
  #pragma unroll
  for (int j = 0; j < 8; ++j) {
    int c = j * 64 + l;
    s += Wbig[(size_t)row * 512 + c] * emb_b[c];
  }
  #pragma unroll
  for (int m = 1; m < 64; m <<= 1) s += __shfl_xor(s, m);
  if (l == 0) out[row] = s + b2[row];
}

__global__ __launch_bounds__(256) void bias_stage2(
    const float* __restrict__ ipW, const float* __restrict__ ipb,
    const float* __restrict__ t1q, const float* __restrict__ t1k,
    float* __restrict__ bqe, float* __restrict__ bke,
    const float* __restrict__ out_W, const float* __restrict__ ln_g,
    const float* __restrict__ ln_b, const float* __restrict__ out_b,
    float* __restrict__ u, float* __restrict__ v) {
  const int t = threadIdx.x, l = t & 63, w = t >> 6;
  const int blk = blockIdx.x;
  if (blk < 256) {
    const int sel = blk >> 7;
    const int row = (blk & 127) * 4 + w;
    const float* Wbig = ipW + (size_t)sel * 262144;
    const float* b1   = sel == 0 ? t1q : t1k;
    const float* b2   = ipb + sel * 512;
    float* out        = sel == 0 ? bqe : bke;
    float s = 0.f;
    #pragma unroll
    for (int j = 0; j < 8; ++j) {
      int c = j * 64 + l;
      s += Wbig[(size_t)row * 512 + c] * b1[c];
    }
    #pragma unroll
    for (int m = 1; m < 64; m <<= 1) s += __shfl_xor(s, m);
    if (l == 0) out[row] = s + b2[row];
  } else {
    const int r4 = (blk - 256) * 4 + w;  // 0..255
    const int row = r4 & 127;
    const float* src = (r4 < 128) ? ln_g : ln_b;
    float s = 0.f;
    #pragma unroll
    for (int j = 0; j < 8; ++j) {
      int c = j * 64 + l;
      s += out_W[(size_t)row * 512 + c] * src[c];
    }
    #pragma unroll
    for (int m = 1; m < 64; m <<= 1) s += __shfl_xor(s, m);
    if (l == 0) {
      if (r4 < 128) u[row] = s;
      else v[row] = s + out_b[row];
    }
  }
}

// ---------------- persistent-W GEMM: C(Mx512) = A(Mx128) @ W(512x128)^T + bias --------
// Transposed MFMA (swap operands): lane holds row=..+l15, cols=..+hi*4+r (4 contiguous)
// -> 8B vector stores, in-lane row stats, 2-shfl reduction.
// HV: epilogue computes hv = xe + softplus(acc+bias), writes hv, atomicAdds row stats.
template <int BIAS_MODE, bool PAD_ACC, bool HV>
__global__ __launch_bounds__(256) void gemm_btp_kernel(
    const uint16_t* __restrict__ A, long long sA,
    const uint16_t* __restrict__ W, long long sW,
    const float* __restrict__ bias, long long sBias,
    uint16_t* __restrict__ C, long long sC,
    int mIter, float* __restrict__ padout,
    const uint16_t* __restrict__ xein, float* __restrict__ ssum,
    float* __restrict__ ssq) {
  __shared__ uint16_t Ws[2][128 * 64];
  __shared__ uint16_t As[2][128 * 64];
  const int t = threadIdx.x, l = t & 63, w = t >> 6;
  const int wr = w >> 1, wc = w & 1, l15 = l & 15, hi = l >> 4;
  const int gx = gridDim.x, gy = gridDim.y;
  const int nwg = gx * gy * gridDim.z;
  const int lin = blockIdx.x + gx * (blockIdx.y + gy * blockIdx.z);
  const int cpx = nwg >> 3;
  const int sw = (nwg & 7) ? lin : ((lin & 7) * cpx + (lin >> 3));
  const int ntile = sw % gx;
  const int rest = sw / gx;
  const int mg = rest % gy, bz = rest / gy;
  const uint16_t* Ab = A + (size_t)bz * sA;
  const uint16_t* Wb = W + (size_t)bz * sW;
  uint16_t* Cb = C + (size_t)bz * sC;
  const float* biasb = bias + (size_t)bz * sBias;
  const int srow = t >> 3;
  const int schunk = (t & 7) * 8;
  const int gchunk = (((t & 7) ^ (srow & 7)) * 8);
  const int rowB0 = ntile * 128;
  #pragma unroll
  for (int kt = 0; kt < 2; ++kt)
    #pragma unroll
    for (int i = 0; i < 4; ++i) {
      const int r = i * 32 + srow;
      gld16(&Ws[kt][r * 64 + schunk], Wb + (size_t)(rowB0 + r) * 128 + kt * 64 + gchunk);
    }
  auto stageA = [&](int u) {
    const int rowA0 = (mg * mIter + (u >> 1)) * 128;
    const int kb = (u & 1) << 6;
    #pragma unroll
    for (int i = 0; i < 4; ++i) {
      const int r = i * 32 + srow;
      gld16(&As[u & 1][r * 64 + schunk], Ab + (size_t)(rowA0 + r) * 128 + kb + gchunk);
    }
  };
  const int rsw = (l15 & 7);
  stageA(0);
  const int U = mIter * 2;
  f32x4 acc[4][4];
  for (int u = 0; u < U; ++u) {
    const int kt = u & 1;
    if (kt == 0) {
      #pragma unroll
      for (int m = 0; m < 4; ++m)
        #pragma unroll
        for (int n = 0; n < 4; ++n) acc[m][n] = (f32x4){0.f, 0.f, 0.f, 0.f};
    }
    if (u + 1 < U) {
      stageA(u + 1);
      asm volatile("s_waitcnt vmcnt(4)" ::: "memory");
    } else {
      asm volatile("s_waitcnt vmcnt(0)" ::: "memory");
    }
    __builtin_amdgcn_s_barrier();
    asm volatile("" ::: "memory");
    #pragma unroll
    for (int ks = 0; ks < 2; ++ks) {
      const int gck = ((ks * 4 + hi) ^ rsw) * 8;
      bf16x8 a[4], bb[4];
      #pragma unroll
      for (int m = 0; m < 4; ++m)
        a[m] = *(const bf16x8*)&As[kt][(wr * 64 + m * 16 + l15) * 64 + gck];
      #pragma unroll
      for (int n = 0; n < 4; ++n)
        bb[n] = *(const bf16x8*)&Ws[kt][(wc * 64 + n * 16 + l15) * 64 + gck];
      // swapped operands -> transposed fragment: lane row = l15, cols = hi*4+r
      #pragma unroll
      for (int m = 0; m < 4; ++m)
        #pragma unroll
        for (int n = 0; n < 4; ++n) acc[m][n] = MFMA16(bb[n], a[m], acc[m][n]);
    }
    asm volatile("" ::: "memory");
    __builtin_amdgcn_s_barrier();
    if (kt == 1) {
      const int rowA0 = (mg * mIter + (u >> 1)) * 128;
      #pragma unroll
      for (int m = 0; m < 4; ++m) {
        const int row = rowA0 + wr * 64 + m * 16 + l15;
        float padp = 0.f, hs = 0.f, hq = 0.f;
        #pragma unroll
        for (int n = 0; n < 4; ++n) {
          const int colb = rowB0 + wc * 64 + n * 16 + hi * 4;
          union { ushort4 v; uint16_t e[4]; } o, xv;
          if constexpr (HV)
            xv.v = *(const ushort4*)&xein[(size_t)row * 512 + colb];
          #pragma unroll
          for (int r = 0; r < 4; ++r) {
            float rv = acc[m][n][r];
            if constexpr (BIAS_MODE == 1) rv += biasb[colb + r];
            if constexpr (PAD_ACC) padp += fabsf(rv);
            if constexpr (HV) {
              const float sp = fmaxf(rv, 0.f) + __logf(1.f + __expf(-fabsf(rv)));
              const float hvv = b2f(xv.e[r]) + sp;
              hs += hvv;
              hq += hvv * hvv;
              o.e[r] = f2b(hvv);
            } else {
              o.e[r] = f2b(rv);
            }
          }
          *(ushort4*)&Cb[(size_t)row * 512 + colb] = o.v;
        }
        if constexpr (PAD_ACC) {
          if (bz == 0) {
            padp += __shfl_xor(padp, 16);
            padp += __shfl_xor(padp, 32);
            if (l < 16) atomicAdd(padout + row, padp);
          }
        }
        if constexpr (HV) {
          hs += __shfl_xor(hs, 16); hs += __shfl_xor(hs, 32);
          hq += __shfl_xor(hq, 16); hq += __shfl_xor(hq, 32);
          if (l < 16) {
            atomicAdd(ssum + row, hs);
            atomicAdd(ssq + row, hq);
          }
        }
      }
    }
  }
}

// ---------------- generic C(MxN) = A(MxK) @ W(NxK)^T (final GEMM; LN fold) ----
// Transposed fragment epilogue: row = ..+l15 (mu/rstd once per m), float4 stores.
template <typename OT, int BIAS_MODE, bool LN>
__global__ __launch_bounds__(256) void gemm_bt_kernel(
    const uint16_t* __restrict__ A, long long sA,
    const uint16_t* __restrict__ W, long long sW,
    const float* __restrict__ bias, long long sBias,
    OT* __restrict__ C, long long sC, int N, int K,
    const float* __restrict__ ssum, const float* __restrict__ ssq,
    const float* __restrict__ uarr, const float* __restrict__ varr) {
  __shared__ uint16_t As[2][128 * 64];
  __shared__ uint16_t Bs[2][128 * 64];
  const int t = threadIdx.x, l = t & 63, w = t >> 6;
  const int wr = w >> 1, wc = w & 1, l15 = l & 15, hi = l >> 4;
  const int gx = gridDim.x, gy = gridDim.y;
  const int nwg = gx * gy * gridDim.z;
  const int lin = blockIdx.x + gx * (blockIdx.y + gy * blockIdx.z);
  const int cpx = nwg >> 3;
  const int sw = (nwg & 7) ? lin : ((lin & 7) * cpx + (lin >> 3));
  const int ntile = sw % gx;
  const int rest = sw / gx;
  const int mtile = rest % gy, bz = rest / gy;
  const uint16_t* Ab = A + (size_t)bz * sA;
  const uint16_t* Wb = W + (size_t)bz * sW;
  OT* Cb = C + (size_t)bz * sC;
  const float* biasb = bias + (size_t)bz * sBias;
  f32x4 acc[4][4];
  #pragma unroll
  for (int m = 0; m < 4; ++m)
    #pragma unroll
    for (int n = 0; n < 4; ++n) acc[m][n] = (f32x4){0.f, 0.f, 0.f, 0.f};
  const int srow = t >> 3;
  const int schunk = (t & 7) * 8;
  const int gchunk = (((t & 7) ^ (srow & 7)) * 8);
  const int nk = K >> 6;
  const int rowA0 = mtile * 128, rowB0 = ntile * 128;
  auto stage = [&](int kt, int buf) {
    const int kb = kt << 6;
    #pragma unroll
    for (int i = 0; i < 4; ++i) {
      const int r = i * 32 + srow;
      gld16(&As[buf][r * 64 + schunk], Ab + (size_t)(rowA0 + r) * K + kb + gchunk);
      gld16(&Bs[buf][r * 64 + schunk], Wb + (size_t)(rowB0 + r) * K + kb + gchunk);
    }
  };
  stage(0, 0);
  const int rsw = (l15 & 7);
  for (int kt = 0; kt < nk; ++kt) {
    const int cur = kt & 1;
    if (kt + 1 < nk) {
      stage(kt + 1, cur ^ 1);
      asm volatile("s_waitcnt vmcnt(8)" ::: "memory");
    } else {
      asm volatile("s_waitcnt vmcnt(0)" ::: "memory");
    }
    __builtin_amdgcn_s_barrier();
    asm volatile("" ::: "memory");
    #pragma unroll
    for (int ks = 0; ks < 2; ++ks) {
      const int gck = ((ks * 4 + hi) ^ rsw) * 8;
      bf16x8 a[4], bb[4];
      #pragma unroll
      for (int m = 0; m < 4; ++m)
        a[m] = *(const bf16x8*)&As[cur][(wr * 64 + m * 16 + l15) * 64 + gck];
      #pragma unroll
      for (int n = 0; n < 4; ++n)
        bb[n] = *(const bf16x8*)&Bs[cur][(wc * 64 + n * 16 + l15) * 64 + gck];
      // swapped operands -> transposed fragment
      #pragma unroll
      for (int m = 0; m < 4; ++m)
        #pragma unroll
        for (int n = 0; n < 4; ++n) acc[m][n] = MFMA16(bb[n], a[m], acc[m][n]);
    }
    asm volatile("" ::: "memory");
    __builtin_amdgcn_s_barrier();
  }
  #pragma unroll
  for (int m = 0; m < 4; ++m) {
    const int row = rowA0 + wr * 64 + m * 16 + l15;
    float mu = 0.f, rstd = 0.f;
    if constexpr (LN) {
      mu = ssum[row] * (1.f / 512.f);
      const float var = ssq[row] * (1.f / 512.f) - mu * mu;
      rstd = rsqrtf(var + 1e-5f);
    }
    #pragma unroll
    for (int n = 0; n < 4; ++n) {
      const int colb = rowB0 + wc * 64 + n * 16 + hi * 4;
      if constexpr (sizeof(OT) == 2) {
        union { ushort4 v; uint16_t e[4]; } o;
        #pragma unroll
        for (int r = 0; r < 4; ++r) {
          float rv;
          if constexpr (LN) {
            rv = rstd * (acc[m][n][r] - mu * uarr[colb + r]) + varr[colb + r];
          } else {
            float bv = 0.f;
            if constexpr (BIAS_MODE == 1) bv = biasb[colb + r];
            rv = acc[m][n][r] + bv;
          }
          o.e[r] = f2b(rv);
        }
        *(ushort4*)&((uint16_t*)Cb)[(size_t)row * N + colb] = o.v;
      } else {
        union { float4 v; float e[4]; } o;
        #pragma unroll
        for (int r = 0; r < 4; ++r) {
          float rv;
          if constexpr (LN) {
            rv = rstd * (acc[m][n][r] - mu * uarr[colb + r]) + varr[colb + r];
          } else {
            float bv = 0.f;
            if constexpr (BIAS_MODE == 1) bv = biasb[colb + r];
            rv = acc[m][n][r] + bv;
          }
          o.e[r] = rv;
        }
        *(float4*)&Cb[(size_t)row * N + colb] = o.v;
      }
    }
  }
}

// ---------------- C = A(MxK) @ B(KxN), B row-major (weight prep only) ----
__global__ __launch_bounds__(256) void gemm_ab_kernel(
    const uint16_t* __restrict__ A, int lda, long long sA,
    const uint16_t* __restrict__ B, int ldb, long long sB,
    uint16_t* __restrict__ C, int ldc, long long sC, int K) {
  __shared__ uint16_t As[128 * 64];
  __shared__ uint16_t Bt[128 * 64];
  const int t = threadIdx.x, l = t & 63, w = t >> 6;
  const int wr = w >> 1, wc = w & 1, l15 = l & 15, hi = l >> 4;
  const int gx = gridDim.x, gy = gridDim.y;
  const int nwg = gx * gy * gridDim.z;
  const int lin = blockIdx.x + gx * (blockIdx.y + gy * blockIdx.z);
  const int cpx = nwg >> 3;
  const int sw = (nwg & 7) ? lin : ((lin & 7) * cpx + (lin >> 3));
  const int ntile = sw % gx;
  const int rest = sw / gx;
  const int mtile = rest % gy, bz = rest / gy;
  const uint16_t* Ab = A + (size_t)bz * sA;
  const uint16_t* Bb = B + (size_t)bz * sB;
  uint16_t* Cb = C + (size_t)bz * sC;
  f32x4 acc[4][4];
  #pragma unroll
  for (int m = 0; m < 4; ++m)
    #pragma unroll
    for (int n = 0; n < 4; ++n) acc[m][n] = (f32x4){0.f, 0.f, 0.f, 0.f};
  const int srow = t >> 3, schunk = (t & 7) * 8;
  const int nk = K >> 6;
  for (int kt = 0; kt < nk; ++kt) {
    const int kb = kt << 6;
    #pragma unroll
    for (int i = 0; i < 4; ++i) {
      const int r = i * 32 + srow;
      gld16(&As[r * 64 + schunk], Ab + (size_t)(mtile * 128 + r) * lda + kb + schunk);
    }
    #pragma unroll
    for (int rd = 0; rd < 4; ++rd) {
      const int id = rd * 256 + t;
      const int kr = id >> 4;
      const int c = (id & 15) * 8;
      u16x8 gv = *(const u16x8*)(Bb + (size_t)(kb + kr) * ldb + ntile * 128 + c);
      #pragma unroll
      for (int j = 0; j < 8; ++j) Bt[(c + j) * 64 + kr] = gv[j];
    }
    __syncthreads();
    #pragma unroll
    for (int ks = 0; ks < 2; ++ks) {
      const int k0 = ks * 32 + hi * 8;
      bf16x8 a[4], bb[4];
      #pragma unroll
      for (int m = 0; m < 4; ++m) a[m] = *(const bf16x8*)&As[(wr * 64 + m * 16 + l15) * 64 + k0];
      #pragma unroll
      for (int n = 0; n < 4; ++n) bb[n] = *(const bf16x8*)&Bt[(wc * 64 + n * 16 + l15) * 64 + k0];
      #pragma unroll
      for (int m = 0; m < 4; ++m)
        #pragma unroll
        for (int n = 0; n < 4; ++n) acc[m][n] = MFMA16(a[m], bb[n], acc[m][n]);
    }
    __syncthreads();
  }
  #pragma unroll
  for (int m = 0; m < 4; ++m) {
    const int row = mtile * 128 + wr * 64 + m * 16 + hi * 4;
    #pragma unroll
    for (int n = 0; n < 4; ++n) {
      const int col = ntile * 128 + wc * 64 + n * 16 + l15;
      #pragma unroll
      for (int r = 0; r < 4; ++r)
        Cb[(size_t)(row + r) * ldc + col] = f2b(acc[m][n][r]);
    }
  }
}

// ---------------- Wg_h[e][d] = sum_o Wke_h[o][e]*Wqe_h[o][d] ; v_h[e] = sum_o Wke_h[o][e]*bqe_h[o]
__global__ __launch_bounds__(256) void gemm_atb_kernel(
    const uint16_t* __restrict__ Wke, const uint16_t* __restrict__ Wqe,
    const float* __restrict__ bqe, uint16_t* __restrict__ Wg,
    float* __restrict__ vh) {
  __shared__ uint16_t At[128 * 64];
  __shared__ uint16_t Bt[128 * 64];
  const int h = blockIdx.x;
  const int t = threadIdx.x, l = t & 63, w = t >> 6;
  const int wr = w >> 1, wc = w & 1, l15 = l & 15, hi = l >> 4;
  const uint16_t* A = Wke + (size_t)h * 16384;
  const uint16_t* B = Wqe + (size_t)h * 16384;
  f32x4 acc[4][4];
  #pragma unroll
  for (int m = 0; m < 4; ++m)
    #pragma unroll
    for (int n = 0; n < 4; ++n) acc[m][n] = (f32x4){0.f, 0.f, 0.f, 0.f};
  float vacc = 0.f;
  for (int kt = 0; kt < 2; ++kt) {
    const int kb = kt << 6;
    #pragma unroll
    for (int rd = 0; rd < 4; ++rd) {
      const int id = rd * 256 + t;
      const int kr = id >> 4;
      const int c = (id & 15) * 8;
      u16x8 ga = *(const u16x8*)(A + (size_t)(kb + kr) * 128 + c);
      u16x8 gb = *(const u16x8*)(B + (size_t)(kb + kr) * 128 + c);
      #pragma unroll
      for (int j = 0; j < 8; ++j) {
        const int row = c + j;
        const int sxz = (((row & 7) ^ ((row >> 3) & 7)) << 3);
        At[row * 64 + (kr ^ sxz)] = ga[j];
        Bt[row * 64 + (kr ^ sxz)] = gb[j];
      }
    }
    __syncthreads();
    if (t < 128) {
      const int sxz = (((t & 7) ^ ((t >> 3) & 7)) << 3);
      for (int o = 0; o < 64; ++o)
        vacc += b2f(At[t * 64 + (o ^ sxz)]) * bqe[h * 128 + kb + o];
    }
    #pragma unroll
    for (int ks = 0; ks < 2; ++ks) {
      bf16x8 a[4], bb[4];
      #pragma unroll
      for (int m = 0; m < 4; ++m) {
        const int mr = wr * 64 + m * 16 + l15;
        const int sxz = (((mr & 7) ^ ((mr >> 3) & 7)) << 3);
        a[m] = *(const bf16x8*)&At[mr * 64 + ((ks * 32 + hi * 8) ^ sxz)];
      }
      #pragma unroll
      for (int n = 0; n < 4; ++n) {
        const int nr = wc * 64 + n * 16 + l15;
        const int sxz = (((nr & 7) ^ ((nr >> 3) & 7)) << 3);
        bb[n] = *(const bf16x8*)&Bt[nr * 64 + ((ks * 32 + hi * 8) ^ sxz)];
      }
      #pragma unroll
      for (int m = 0; m < 4; ++m)
        #pragma unroll
        for (int n = 0; n < 4; ++n) acc[m][n] = MFMA16(a[m], bb[n], acc[m][n]);
    }
    __syncthreads();
  }
  if (t < 128) vh[h * 128 + t] = vacc;
  #pragma unroll
  for (int m = 0; m < 4; ++m) {
    const int row = wr * 64 + m * 16 + hi * 4;
    #pragma unroll
    for (int n = 0; n < 4; ++n) {
      const int col = wc * 64 + n * 16 + l15;
      #pragma unroll
      for (int r = 0; r < 4; ++r)
        Wg[(size_t)h * 16384 + (size_t)(row + r) * 128 + col] = f2b(acc[m][n][r]);
    }
  }
}

// ---------------- fused attention + PV (512 threads / 8 waves) ----------------------
__global__ __launch_bounds__(512) void att_fused(
    const uint16_t* __restrict__ xg, const uint16_t* __restrict__ Wg,
    const float* __restrict__ vh, const float* __restrict__ wts,
    const float* __restrict__ padsum, uint16_t* __restrict__ tout) {
  __shared__ uint16_t Xr[2][128 * 64];
  __shared__ uint16_t GP[2][128 * 64];
  __shared__ float bS[4][128];
  const int blk = blockIdx.x;
  const int b = (blk & 7) * 64 + (blk >> 3);
  const int t = threadIdx.x, l = t & 63, wband = t >> 6;
  const int l15 = l & 15, hi = l >> 4;
  const int srow = t >> 3;
  const int schunk = (t & 7) * 8;
  const int gchunk = (((t & 7) ^ (srow & 7)) * 8);
  const float SCALE = 0.088388347648318447f;
  const int rsw = (l15 & 7);

  const uint16_t* xb = xg + (size_t)b * 16384;
  #pragma unroll
  for (int kt = 0; kt < 2; ++kt)
    #pragma unroll
    for (int i = 0; i < 2; ++i) {
      const int r = i * 64 + srow;
      gld16(&Xr[kt][r * 64 + schunk], xb + (size_t)r * 128 + kt * 64 + gchunk);
      gld16(&GP[kt][r * 64 + schunk], Wg + (size_t)r * 128 + kt * 64 + gchunk);
    }
  asm volatile("s_waitcnt vmcnt(0)" ::: "memory");
  __builtin_amdgcn_s_barrier();
  {
    const int hh = t >> 7, j = t & 127;
    float s = 0.f;
    for (int e = 0; e < 128; ++e) {
      const int c = e & 63;
      const int addr = j * 64 + ((((c >> 3) ^ (j & 7)) << 3) | (c & 7));
      s += b2f(Xr[e >> 6][addr]) * vh[hh * 128 + e];
    }
    bS[hh][j] = s * SCALE +
                ((padsum[(size_t)b * 128 + j] == 0.f) ? -__builtin_inff() : 0.f);
  }

  f32x4 awacc[8];
  #pragma unroll
  for (int n = 0; n < 8; ++n) awacc[n] = (f32x4){0.f, 0.f, 0.f, 0.f};
  u16x8 wreg[4];
  u16x8 xtr[4];

  for (int h = 0; h < 4; ++h) {
    f32x4 pacc[8];
    #pragma unroll
    for (int n = 0; n < 8; ++n) pacc[n] = (f32x4){0.f, 0.f, 0.f, 0.f};
    __builtin_amdgcn_s_setprio(1);
    #pragma unroll
    for (int kt = 0; kt < 2; ++kt)
      #pragma unroll
      for (int ks = 0; ks < 2; ++ks) {
        const int gck = ((ks * 4 + hi) ^ rsw) * 8;
        bf16x8 a, bb[8];
        a = *(const bf16x8*)&Xr[kt][(wband * 16 + l15) * 64 + gck];
        #pragma unroll
        for (int n = 0; n < 8; ++n)
          bb[n] = *(const bf16x8*)&GP[kt][(n * 16 + l15) * 64 + gck];
        #pragma unroll
        for (int n = 0; n < 8; ++n) pacc[n] = MFMA16(a, bb[n], pacc[n]);
      }
    __builtin_amdgcn_s_setprio(0);
    if (h + 1 < 4) {
      #pragma unroll
      for (int kt = 0; kt < 2; ++kt)
        #pragma unroll
        for (int i = 0; i < 2; ++i) {
          const int r = i * 64 + srow;
          wreg[kt * 2 + i] = *(const u16x8*)(Wg + (size_t)(h + 1) * 16384 +
                                             (size_t)r * 128 + kt * 64 + gchunk);
        }
    }
    __builtin_amdgcn_s_barrier();
    #pragma unroll
    for (int n = 0; n < 8; ++n) {
      const int cl = n * 16 + l15;
      const int c = cl & 63;
      #pragma unroll
      for (int r = 0; r < 4; ++r) {
        const int rr = wband * 16 + hi * 4 + r;
        GP[cl >> 6][rr * 64 + ((((c >> 3) ^ (rr & 7)) << 3) | (c & 7))] =
            f2b(pacc[n][r]);
      }
    }
    __builtin_amdgcn_s_barrier();
    f32x4 sacc[8];
    #pragma unroll
    for (int n = 0; n < 8; ++n) sacc[n] = (f32x4){0.f, 0.f, 0.f, 0.f};
    __builtin_amdgcn_s_setprio(1);
    #pragma unroll
    for (int kt = 0; kt < 2; ++kt)
      #pragma unroll
      for (int ks = 0; ks < 2; ++ks) {
        const int gck = ((ks * 4 + hi) ^ rsw) * 8;
        bf16x8 a, bb[8];
        a = *(const bf16x8*)&GP[kt][(wband * 16 + l15) * 64 + gck];
        #pragma unroll
        for (int n = 0; n < 8; ++n)
          bb[n] = *(const bf16x8*)&Xr[kt][(n * 16 + l15) * 64 + gck];
        #pragma unroll
        for (int n = 0; n < 8; ++n) sacc[n] = MFMA16(a, bb[n], sacc[n]);
      }
    __builtin_amdgcn_s_setprio(0);
    if (h == 3) {
      #pragma unroll
      for (int i = 0; i < 4; ++i) {
        const int id = i * 512 + t;
        const int jr = id >> 4;
        const int cc = (id & 15) * 8;
        xtr[i] = *(const u16x8*)(xb + (size_t)jr * 128 + cc);
      }
    }
    #pragma unroll
    for (int r = 0; r < 4; ++r) {
      float e[8], z = 0.f;
      #pragma unroll
      for (int n = 0; n < 8; ++n) {
        e[n] = __expf(sacc[n][r] * SCALE + bS[h][n * 16 + l15]);
        z += e[n];
      }
      z += __shfl_xor(z, 1); z += __shfl_xor(z, 2);
      z += __shfl_xor(z, 4); z += __shfl_xor(z, 8);
      const float zi = 1.f / z;
      #pragma unroll
      for (int n = 0; n < 8; ++n) awacc[n][r] += e[n] * zi;
    }
    if (h + 1 < 4) {
      __builtin_amdgcn_s_barrier();
      asm volatile("s_waitcnt vmcnt(0)" ::: "memory");
      #pragma unroll
      for (int kt = 0; kt < 2; ++kt)
        #pragma unroll
        for (int i = 0; i < 2; ++i) {
          const int r = i * 64 + srow;
          *(u16x8*)&GP[kt][r * 64 + schunk] = wreg[kt * 2 + i];
        }
      __builtin_amdgcn_s_barrier();
    }
  }
  float wv[8];
  #pragma unroll
  for (int n = 0; n < 8; ++n) wv[n] = wts[(size_t)b * 128 + n * 16 + l15];
  __builtin_amdgcn_s_barrier();
  #pragma unroll
  for (int r = 0; r < 4; ++r) {
    float z = 0.f;
    #pragma unroll
    for (int n = 0; n < 8; ++n) z += awacc[n][r] * wv[n];
    z += __shfl_xor(z, 1); z += __shfl_xor(z, 2);
    z += __shfl_xor(z, 4); z += __shfl_xor(z, 8);
    const float zi = 1.f / z;
    const int rr = wband * 16 + hi * 4 + r;
    #pragma unroll
    for (int n = 0; n < 8; ++n) {
      const int cl = n * 16 + l15;
      const int c = cl & 63;
      GP[cl >> 6][rr * 64 + ((((c >> 3) ^ (rr & 7)) << 3) | (c & 7))] =
          f2b(awacc[n][r] * wv[n] * zi);
    }
  }
  asm volatile("s_waitcnt vmcnt(0)" ::: "memory");
  #pragma unroll
  for (int i = 0; i < 4; ++i) {
    const int id = i * 512 + t;
    const int jr = id >> 4;
    const int cc = (id & 15) * 8;
    const int kt2 = jr >> 6, kr = jr & 63;
    #pragma unroll
    for (int j = 0; j < 8; ++j) {
      const int drow = cc + j;
      const int sxz = (((drow & 7) ^ ((drow >> 3) & 7)) << 3);
      Xr[kt2][drow * 64 + (kr ^ sxz)] = xtr[i][j];
    }
  }
  __builtin_amdgcn_s_barrier();
  f32x4 tacc[8];
  #pragma unroll
  for (int n = 0; n < 8; ++n) tacc[n] = (f32x4){0.f, 0.f, 0.f, 0.f};
  __builtin_amdgcn_s_setprio(1);
  #pragma unroll
  for (int kt = 0; kt < 2; ++kt)
    #pragma unroll
    for (int ks = 0; ks < 2; ++ks) {
      const int gck = ((ks * 4 + hi) ^ rsw) * 8;
      bf16x8 a, bb[8];
      a = *(const bf16x8*)&GP[kt][(wband * 16 + l15) * 64 + gck];
      #pragma unroll
      for (int n = 0; n < 8; ++n) {
        const int nr = n * 16 + l15;
        const int sxz = (((nr & 7) ^ ((nr >> 3) & 7)) << 3);
        bb[n] = *(const bf16x8*)&Xr[kt][nr * 64 + ((ks * 32 + hi * 8) ^ sxz)];
      }
      #pragma unroll
      for (int n = 0; n < 8; ++n) tacc[n] = MFMA16(a, bb[n], tacc[n]);
    }
  __builtin_amdgcn_s_setprio(0);
  #pragma unroll
  for (int r = 0; r < 4; ++r) {
    const int row = wband * 16 + hi * 4 + r;
    #pragma unroll
    for (int n = 0; n < 8; ++n) {
      const int col = n * 16 + l15;
      tout[(size_t)b * 16384 + (size_t)row * 128 + col] = f2b(tacc[n][r]);
    }
  }
}

// =======================================================================================
extern "C" void kernel_launch(void* const* d_in, const int* in_sizes, int n_in,
                              void* d_out, int out_size, void* d_ws, size_t ws_size,
                              hipStream_t stream) {
  (void)in_sizes; (void)n_in; (void)out_size; (void)ws_size;
  const float* x     = (const float*)d_in[0];
  const float* wts   = (const float*)d_in[1];
  const float* emb_W = (const float*)d_in[2];
  const float* emb_b = (const float*)d_in[3];
  const float* wq_W  = (const float*)d_in[4];
  const float* wq_b  = (const float*)d_in[5];
  const float* wk_W  = (const float*)d_in[6];
  const float* wk_b  = (const float*)d_in[7];
  const float* wv_W  = (const float*)d_in[8];
  const float* wv_b  = (const float*)d_in[9];
  const float* ipW   = (const float*)d_in[10];
  const float* ipb   = (const float*)d_in[11];
  const float* ln_g  = (const float*)d_in[12];
  const float* ln_b  = (const float*)d_in[13];
  const float* out_W = (const float*)d_in[14];
  const float* out_b = (const float*)d_in[15];

  char* ws = (char*)d_ws;
  size_t off = 0;
  auto alloc = [&](size_t bytes) { void* p = ws + off; off += (bytes + 255) & ~(size_t)255; return p; };
  uint16_t* wqW_bf = (uint16_t*)alloc(524288);
  uint16_t* wkW_bf = (uint16_t*)alloc(524288);
  uint16_t* ip_bf  = (uint16_t*)alloc(1048576);
  uint16_t* owW_bf = (uint16_t*)alloc(131072);     // Wg2 = out_W * ln_g
  uint16_t* Wqc    = (uint16_t*)alloc(524288);     // contiguous Wqc,Wkc,Wvc
  uint16_t* Wkc    = (uint16_t*)alloc(524288);
  uint16_t* Wvc    = (uint16_t*)alloc(524288);
  uint16_t* embW2  = (uint16_t*)alloc(131072);     // contiguous embW2,Wqe,Wke,Wve
  uint16_t* Wqe    = (uint16_t*)alloc(131072);
  uint16_t* Wke    = (uint16_t*)alloc(131072);
  uint16_t* Wve    = (uint16_t*)alloc(131072);
  uint16_t* Wg     = (uint16_t*)alloc(131072);
  float*    vhbuf  = (float*)alloc(2048);
  float*    t1q    = (float*)alloc(2048);
  float*    t1k    = (float*)alloc(2048);
  float*    biasE  = (float*)alloc(2048);
  float*    bqe    = (float*)alloc(2048);
  float*    bke    = (float*)alloc(2048);
  float*    bve    = (float*)alloc(2048);
  float*    uarr   = (float*)alloc(2048);
  float*    varr   = (float*)alloc(2048);
  float*    pad    = (float*)alloc(262144);
  float*    ssum   = (float*)alloc(262144);
  float*    ssq    = (float*)alloc(262144);
  uint16_t* xe     = (uint16_t*)alloc(67108864);
  uint16_t* B1     = (uint16_t*)alloc(67108864);   // t
  uint16_t* B2     = (uint16_t*)alloc(67108864);   // hv

  uint16_t* x_bf = (uint16_t*)d_out + 8388608;     // d_out upper 16 MiB
  uint16_t* tb   = B1;
  uint16_t* hv   = B2;

  const int TB = 256;
  pack_all<<<9600, TB, 0, stream>>>(x, emb_W, wq_W, wk_W, wv_W, ipW, out_W, ln_g,
                                    x_bf, embW2, wqW_bf, wkW_bf, Wvc, ip_bf, owW_bf);
  bias_stage1<<<384, TB, 0, stream>>>(wq_W, wk_W, wv_W, emb_b, wq_b, wk_b, wv_b,
                                      t1q, t1k, bve, pad, biasE, ssum, ssq);
  bias_stage2<<<320, TB, 0, stream>>>(ipW, ipb, t1q, t1k, bqe, bke,
                                      out_W, ln_g, ln_b, out_b, uarr, varr);
  gemm_ab_kernel<<<dim3(4, 4, 2), TB, 0, stream>>>(ip_bf, 512, 262144, wqW_bf, 512, 262144,
                                                   Wqc, 512, 262144, 512);
  gemm_ab_kernel<<<dim3(1, 4, 3), TB, 0, stream>>>(Wqc, 512, 262144, embW2, 128, 0,
                                                   Wqe, 128, 65536, 512);
  gemm_atb_kernel<<<4, TB, 0, stream>>>(Wke, Wqe, bqe, Wg, vhbuf);
  // xe = x @ emb_W^T + emb_b (persistent W; fused pad accumulation)
  gemm_btp_kernel<1, true, false><<<dim3(4, 128, 1), TB, 0, stream>>>(
      x_bf, 0, embW2, 0, biasE, 0, xe, 0, 4, pad, nullptr, nullptr, nullptr);
  // fused attention + PV -> t
  att_fused<<<512, 512, 0, stream>>>(x_bf, Wg, vhbuf, wts, pad, tb);
  // hv = xe + softplus(t @ Wve^T + bve); row stats accumulated via atomics
  gemm_btp_kernel<1, false, true><<<dim3(4, 128, 1), TB, 0, stream>>>(
      tb, 0, Wve, 0, bve, 0, hv, 0, 4, nullptr, xe, ssum, ssq);
  // out = LN-fold: rstd*(hv@Wg2^T - mu*u) + v, f32 -> d_out
  gemm_bt_kernel<float, 0, true><<<dim3(1, 512, 1), TB, 0, stream>>>(
      hv, 0, owW_bf, 0, nullptr, 0, (float*)d_out, 0, 128, 512,
      ssum, ssq, uarr, varr);
}

// Round 30
// 214.266 us; speedup vs baseline: 1.2865x; 1.0351x over previous
//
#include <hip/hip_runtime.h>
#include <stdint.h>

// Shapes (fixed): B=512, N=128, E=128, H=4, D=512, hd=128.

typedef __attribute__((ext_vector_type(8))) __bf16 bf16x8;
typedef __attribute__((ext_vector_type(8))) uint16_t u16x8;
typedef __attribute__((ext_vector_type(4))) float f32x4;

__device__ __forceinline__ float b2f(uint16_t h) {
  union { uint32_t u; float f; } c; c.u = ((uint32_t)h) << 16; return c.f;
}
__device__ __forceinline__ uint16_t f2b(float f) {
  __bf16 h = (__bf16)f;
  union { __bf16 b; uint16_t u; } c; c.b = h; return c.u;
}
__device__ __forceinline__ void gld16(void* lds, const void* g) {
  __builtin_amdgcn_global_load_lds(
      (const __attribute__((address_space(1))) uint32_t*)(g),
      (__attribute__((address_space(3))) uint32_t*)(lds),
      16, 0, 0);
}

#define MFMA16(a, b, c) __builtin_amdgcn_mfma_f32_16x16x32_bf16((a), (b), (c), 0, 0, 0)

// ---------------- merged pack: x + all weights (out_W scaled by ln_g -> Wg2) ----------
__global__ __launch_bounds__(256) void pack_all(
    const float* __restrict__ x,
    const float* __restrict__ emb_W, const float* __restrict__ wq_W,
    const float* __restrict__ wk_W, const float* __restrict__ wv_W,
    const float* __restrict__ ipW, const float* __restrict__ out_W,
    const float* __restrict__ ln_g,
    uint16_t* __restrict__ x_bf,
    uint16_t* __restrict__ embW2, uint16_t* __restrict__ wqW_bf,
    uint16_t* __restrict__ wkW_bf, uint16_t* __restrict__ Wvc,
    uint16_t* __restrict__ ip_bf, uint16_t* __restrict__ owW_bf) {
  int i = blockIdx.x * 256 + threadIdx.x;
  if (i < 2097152) {
    float4 v = ((const float4*)x)[i];
    ushort4 o;
    o.x = f2b(v.x); o.y = f2b(v.y); o.z = f2b(v.z); o.w = f2b(v.w);
    ((ushort4*)x_bf)[i] = o;
    return;
  }
  int i2 = i - 2097152;
  if (i2 >= 360448) return;
  if (i2 >= 344064) {  // out_W scaled by ln_g -> Wg2
    const int off = i2 - 344064;
    float4 v = ((const float4*)out_W)[off];
    const int base = off * 4;
    ushort4 o;
    o.x = f2b(v.x * ln_g[(base + 0) & 511]);
    o.y = f2b(v.y * ln_g[(base + 1) & 511]);
    o.z = f2b(v.z * ln_g[(base + 2) & 511]);
    o.w = f2b(v.w * ln_g[(base + 3) & 511]);
    ((ushort4*)owW_bf)[off] = o;
    return;
  }
  const float* src; uint16_t* dst; int off;
  if (i2 < 16384)       { src = emb_W; dst = embW2;  off = i2; }
  else if (i2 < 81920)  { src = wq_W;  dst = wqW_bf; off = i2 - 16384; }
  else if (i2 < 147456) { src = wk_W;  dst = wkW_bf; off = i2 - 81920; }
  else if (i2 < 212992) { src = wv_W;  dst = Wvc;    off = i2 - 147456; }
  else                  { src = ipW;   dst = ip_bf;  off = i2 - 212992; }
  float4 v = ((const float4*)src)[off];
  ushort4 o;
  o.x = f2b(v.x); o.y = f2b(v.y); o.z = f2b(v.z); o.w = f2b(v.w);
  ((ushort4*)dst)[off] = o;
}

// ---------------- fused bias folds + zero-init (pad, stats) + emb_b copy ----------------
__global__ __launch_bounds__(256) void bias_stage1(
    const float* __restrict__ wq_W, const float* __restrict__ wk_W,
    const float* __restrict__ wv_W, const float* __restrict__ emb_b,
    const float* __restrict__ wq_b, const float* __restrict__ wk_b,
    const float* __restrict__ wv_b,
    float* __restrict__ t1q, float* __restrict__ t1k, float* __restrict__ bve,
    float* __restrict__ pad_init, float* __restrict__ biasE,
    float* __restrict__ ssum, float* __restrict__ ssq) {
  const int gid = blockIdx.x * 256 + threadIdx.x;
  if (gid < 65536) { pad_init[gid] = 0.f; ssum[gid] = 0.f; ssq[gid] = 0.f; }
  if (gid < 512) biasE[gid] = emb_b[gid];
  const int t = threadIdx.x, l = t & 63, w = t >> 6;
  const int sel = blockIdx.x >> 7;
  const int row = (blockIdx.x & 127) * 4 + w;
  const float* Wbig = sel == 0 ? wq_W : (sel == 1 ? wk_W : wv_W);
  const float* b2   = sel == 0 ? wq_b : (sel == 1 ? wk_b : wv_b);
  float* out        = sel == 0 ? t1q  : (sel == 1 ? t1k  : bve);
  float s = 0.f;
  #pragma unroll
  for (int j = 0; j < 8; ++j) {
    int c = j * 64 + l;
    s += Wbig[(size_t)row * 512 + c] * emb_b[c];
  }
  #pragma unroll
  for (int m = 1; m < 64; m <<= 1) s += __shfl_xor(s, m);
  if (l == 0) out[row] = s + b2[row];
}

__global__ __launch_bounds__(256) void bias_stage2(
    const float* __restrict__ ipW, const float* __restrict__ ipb,
    const float* __restrict__ t1q, const float* __restrict__ t1k,
    float* __restrict__ bqe, float* __restrict__ bke,
    const float* __restrict__ out_W, const float* __restrict__ ln_g,
    const float* __restrict__ ln_b, const float* __restrict__ out_b,
    float* __restrict__ u, float* __restrict__ v) {
  const int t = threadIdx.x, l = t & 63, w = t >> 6;
  const int blk = blockIdx.x;
  if (blk < 256) {
    const int sel = blk >> 7;
    const int row = (blk & 127) * 4 + w;
    const float* Wbig = ipW + (size_t)sel * 262144;
    const float* b1   = sel == 0 ? t1q : t1k;
    const float* b2   = ipb + sel * 512;
    float* out        = sel == 0 ? bqe : bke;
    float s = 0.f;
    #pragma unroll
    for (int j = 0; j < 8; ++j) {
      int c = j * 64 + l;
      s += Wbig[(size_t)row * 512 + c] * b1[c];
    }
    #pragma unroll
    for (int m = 1; m < 64; m <<= 1) s += __shfl_xor(s, m);
    if (l == 0) out[row] = s + b2[row];
  } else {
    const int r4 = (blk - 256) * 4 + w;  // 0..255
    const int row = r4 & 127;
    const float* src = (r4 < 128) ? ln_g : ln_b;
    float s = 0.f;
    #pragma unroll
    for (int j = 0; j < 8; ++j) {
      int c = j * 64 + l;
      s += out_W[(size_t)row * 512 + c] * src[c];
    }
    #pragma unroll
    for (int m = 1; m < 64; m <<= 1) s += __shfl_xor(s, m);
    if (l == 0) {
      if (r4 < 128) u[row] = s;
      else v[row] = s + out_b[row];
    }
  }
}

// ---------------- persistent-W GEMM: C(Mx512) = A(Mx128) @ W(512x128)^T + bias --------
// 512 threads / 8 waves per block, SAME 128x128 tile + 64KB LDS -> 16 waves/CU
// (was 8). Each wave: 32x64 sub-tile, acc[2][4]. Staging: 2 gld16/thread (vmcnt 2).
// Transposed MFMA epilogue: lane row=..+l15, cols=..+hi*4+r, vector stores.
template <int BIAS_MODE, bool PAD_ACC, bool HV>
__global__ __launch_bounds__(512, 4) void gemm_btp_kernel(
    const uint16_t* __restrict__ A, long long sA,
    const uint16_t* __restrict__ W, long long sW,
    const float* __restrict__ bias, long long sBias,
    uint16_t* __restrict__ C, long long sC,
    int mIter, float* __restrict__ padout,
    const uint16_t* __restrict__ xein, float* __restrict__ ssum,
    float* __restrict__ ssq) {
  __shared__ uint16_t Ws[2][128 * 64];
  __shared__ uint16_t As[2][128 * 64];
  const int t = threadIdx.x, l = t & 63, w = t >> 6;   // w in [0,8)
  const int wr = w >> 1, wc = w & 1, l15 = l & 15, hi = l >> 4;
  const int gx = gridDim.x, gy = gridDim.y;
  const int nwg = gx * gy * gridDim.z;
  const int lin = blockIdx.x + gx * (blockIdx.y + gy * blockIdx.z);
  const int cpx = nwg >> 3;
  const int sw = (nwg & 7) ? lin : ((lin & 7) * cpx + (lin >> 3));
  const int ntile = sw % gx;
  const int rest = sw / gx;
  const int mg = rest % gy, bz = rest / gy;
  const uint16_t* Ab = A + (size_t)bz * sA;
  const uint16_t* Wb = W + (size_t)bz * sW;
  uint16_t* Cb = C + (size_t)bz * sC;
  const float* biasb = bias + (size_t)bz * sBias;
  const int srow = t >> 3;            // [0,64)
  const int schunk = (t & 7) * 8;
  const int gchunk = (((t & 7) ^ (srow & 7)) * 8);
  const int rowB0 = ntile * 128;
  #pragma unroll
  for (int kt = 0; kt < 2; ++kt)
    #pragma unroll
    for (int i = 0; i < 2; ++i) {
      const int r = i * 64 + srow;
      gld16(&Ws[kt][r * 64 + schunk], Wb + (size_t)(rowB0 + r) * 128 + kt * 64 + gchunk);
    }
  auto stageA = [&](int u) {
    const int rowA0 = (mg * mIter + (u >> 1)) * 128;
    const int kb = (u & 1) << 6;
    #pragma unroll
    for (int i = 0; i < 2; ++i) {
      const int r = i * 64 + srow;
      gld16(&As[u & 1][r * 64 + schunk], Ab + (size_t)(rowA0 + r) * 128 + kb + gchunk);
    }
  };
  const int rsw = (l15 & 7);
  stageA(0);
  const int U = mIter * 2;
  f32x4 acc[2][4];
  for (int u = 0; u < U; ++u) {
    const int kt = u & 1;
    if (kt == 0) {
      #pragma unroll
      for (int m = 0; m < 2; ++m)
        #pragma unroll
        for (int n = 0; n < 4; ++n) acc[m][n] = (f32x4){0.f, 0.f, 0.f, 0.f};
    }
    if (u + 1 < U) {
      stageA(u + 1);
      asm volatile("s_waitcnt vmcnt(2)" ::: "memory");
    } else {
      asm volatile("s_waitcnt vmcnt(0)" ::: "memory");
    }
    __builtin_amdgcn_s_barrier();
    asm volatile("" ::: "memory");
    #pragma unroll
    for (int ks = 0; ks < 2; ++ks) {
      const int gck = ((ks * 4 + hi) ^ rsw) * 8;
      bf16x8 a[2], bb[4];
      #pragma unroll
      for (int m = 0; m < 2; ++m)
        a[m] = *(const bf16x8*)&As[kt][(wr * 32 + m * 16 + l15) * 64 + gck];
      #pragma unroll
      for (int n = 0; n < 4; ++n)
        bb[n] = *(const bf16x8*)&Ws[kt][(wc * 64 + n * 16 + l15) * 64 + gck];
      // swapped operands -> transposed fragment: lane row = l15, cols = hi*4+r
      #pragma unroll
      for (int m = 0; m < 2; ++m)
        #pragma unroll
        for (int n = 0; n < 4; ++n) acc[m][n] = MFMA16(bb[n], a[m], acc[m][n]);
    }
    asm volatile("" ::: "memory");
    __builtin_amdgcn_s_barrier();
    if (kt == 1) {
      const int rowA0 = (mg * mIter + (u >> 1)) * 128;
      #pragma unroll
      for (int m = 0; m < 2; ++m) {
        const int row = rowA0 + wr * 32 + m * 16 + l15;
        float padp = 0.f, hs = 0.f, hq = 0.f;
        #pragma unroll
        for (int n = 0; n < 4; ++n) {
          const int colb = rowB0 + wc * 64 + n * 16 + hi * 4;
          union { ushort4 v; uint16_t e[4]; } o, xv;
          if constexpr (HV)
            xv.v = *(const ushort4*)&xein[(size_t)row * 512 + colb];
          #pragma unroll
          for (int r = 0; r < 4; ++r) {
            float rv = acc[m][n][r];
            if constexpr (BIAS_MODE == 1) rv += biasb[colb + r];
            if constexpr (PAD_ACC) padp += fabsf(rv);
            if constexpr (HV) {
              const float sp = fmaxf(rv, 0.f) + __logf(1.f + __expf(-fabsf(rv)));
              const float hvv = b2f(xv.e[r]) + sp;
              hs += hvv;
              hq += hvv * hvv;
              o.e[r] = f2b(hvv);
            } else {
              o.e[r] = f2b(rv);
            }
          }
          *(ushort4*)&Cb[(size_t)row * 512 + colb] = o.v;
        }
        if constexpr (PAD_ACC) {
          if (bz == 0) {
            padp += __shfl_xor(padp, 16);
            padp += __shfl_xor(padp, 32);
            if (l < 16) atomicAdd(padout + row, padp);
          }
        }
        if constexpr (HV) {
          hs += __shfl_xor(hs, 16); hs += __shfl_xor(hs, 32);
          hq += __shfl_xor(hq, 16); hq += __shfl_xor(hq, 32);
          if (l < 16) {
            atomicAdd(ssum + row, hs);
            atomicAdd(ssq + row, hq);
          }
        }
      }
    }
  }
}

// ---------------- generic C(MxN) = A(MxK) @ W(NxK)^T (final GEMM; LN fold) ----
// Transposed fragment epilogue: row = ..+l15 (mu/rstd once per m), float4 stores.
template <typename OT, int BIAS_MODE, bool LN>
__global__ __launch_bounds__(256) void gemm_bt_kernel(
    const uint16_t* __restrict__ A, long long sA,
    const uint16_t* __restrict__ W, long long sW,
    const float* __restrict__ bias, long long sBias,
    OT* __restrict__ C, long long sC, int N, int K,
    const float* __restrict__ ssum, const float* __restrict__ ssq,
    const float* __restrict__ uarr, const float* __restrict__ varr) {
  __shared__ uint16_t As[2][128 * 64];
  __shared__ uint16_t Bs[2][128 * 64];
  const int t = threadIdx.x, l = t & 63, w = t >> 6;
  const int wr = w >> 1, wc = w & 1, l15 = l & 15, hi = l >> 4;
  const int gx = gridDim.x, gy = gridDim.y;
  const int nwg = gx * gy * gridDim.z;
  const int lin = blockIdx.x + gx * (blockIdx.y + gy * blockIdx.z);
  const int cpx = nwg >> 3;
  const int sw = (nwg & 7) ? lin : ((lin & 7) * cpx + (lin >> 3));
  const int ntile = sw % gx;
  const int rest = sw / gx;
  const int mtile = rest % gy, bz = rest / gy;
  const uint16_t* Ab = A + (size_t)bz * sA;
  const uint16_t* Wb = W + (size_t)bz * sW;
  OT* Cb = C + (size_t)bz * sC;
  const float* biasb = bias + (size_t)bz * sBias;
  f32x4 acc[4][4];
  #pragma unroll
  for (int m = 0; m < 4; ++m)
    #pragma unroll
    for (int n = 0; n < 4; ++n) acc[m][n] = (f32x4){0.f, 0.f, 0.f, 0.f};
  const int srow = t >> 3;
  const int schunk = (t & 7) * 8;
  const int gchunk = (((t & 7) ^ (srow & 7)) * 8);
  const int nk = K >> 6;
  const int rowA0 = mtile * 128, rowB0 = ntile * 128;
  auto stage = [&](int kt, int buf) {
    const int kb = kt << 6;
    #pragma unroll
    for (int i = 0; i < 4; ++i) {
      const int r = i * 32 + srow;
      gld16(&As[buf][r * 64 + schunk], Ab + (size_t)(rowA0 + r) * K + kb + gchunk);
      gld16(&Bs[buf][r * 64 + schunk], Wb + (size_t)(rowB0 + r) * K + kb + gchunk);
    }
  };
  stage(0, 0);
  const int rsw = (l15 & 7);
  for (int kt = 0; kt < nk; ++kt) {
    const int cur = kt & 1;
    if (kt + 1 < nk) {
      stage(kt + 1, cur ^ 1);
      asm volatile("s_waitcnt vmcnt(8)" ::: "memory");
    } else {
      asm volatile("s_waitcnt vmcnt(0)" ::: "memory");
    }
    __builtin_amdgcn_s_barrier();
    asm volatile("" ::: "memory");
    #pragma unroll
    for (int ks = 0; ks < 2; ++ks) {
      const int gck = ((ks * 4 + hi) ^ rsw) * 8;
      bf16x8 a[4], bb[4];
      #pragma unroll
      for (int m = 0; m < 4; ++m)
        a[m] = *(const bf16x8*)&As[cur][(wr * 64 + m * 16 + l15) * 64 + gck];
      #pragma unroll
      for (int n = 0; n < 4; ++n)
        bb[n] = *(const bf16x8*)&Bs[cur][(wc * 64 + n * 16 + l15) * 64 + gck];
      // swapped operands -> transposed fragment
      #pragma unroll
      for (int m = 0; m < 4; ++m)
        #pragma unroll
        for (int n = 0; n < 4; ++n) acc[m][n] = MFMA16(bb[n], a[m], acc[m][n]);
    }
    asm volatile("" ::: "memory");
    __builtin_amdgcn_s_barrier();
  }
  #pragma unroll
  for (int m = 0; m < 4; ++m) {
    const int row = rowA0 + wr * 64 + m * 16 + l15;
    float mu = 0.f, rstd = 0.f;
    if constexpr (LN) {
      mu = ssum[row] * (1.f / 512.f);
      const float var = ssq[row] * (1.f / 512.f) - mu * mu;
      rstd = rsqrtf(var + 1e-5f);
    }
    #pragma unroll
    for (int n = 0; n < 4; ++n) {
      const int colb = rowB0 + wc * 64 + n * 16 + hi * 4;
      if constexpr (sizeof(OT) == 2) {
        union { ushort4 v; uint16_t e[4]; } o;
        #pragma unroll
        for (int r = 0; r < 4; ++r) {
          float rv;
          if constexpr (LN) {
            rv = rstd * (acc[m][n][r] - mu * uarr[colb + r]) + varr[colb + r];
          } else {
            float bv = 0.f;
            if constexpr (BIAS_MODE == 1) bv = biasb[colb + r];
            rv = acc[m][n][r] + bv;
          }
          o.e[r] = f2b(rv);
        }
        *(ushort4*)&((uint16_t*)Cb)[(size_t)row * N + colb] = o.v;
      } else {
        union { float4 v; float e[4]; } o;
        #pragma unroll
        for (int r = 0; r < 4; ++r) {
          float rv;
          if constexpr (LN) {
            rv = rstd * (acc[m][n][r] - mu * uarr[colb + r]) + varr[colb + r];
          } else {
            float bv = 0.f;
            if constexpr (BIAS_MODE == 1) bv = biasb[colb + r];
            rv = acc[m][n][r] + bv;
          }
          o.e[r] = rv;
        }
        *(float4*)&Cb[(size_t)row * N + colb] = o.v;
      }
    }
  }
}

// ---------------- C = A(MxK) @ B(KxN), B row-major (weight prep only) ----
__global__ __launch_bounds__(256) void gemm_ab_kernel(
    const uint16_t* __restrict__ A, int lda, long long sA,
    const uint16_t* __restrict__ B, int ldb, long long sB,
    uint16_t* __restrict__ C, int ldc, long long sC, int K) {
  __shared__ uint16_t As[128 * 64];
  __shared__ uint16_t Bt[128 * 64];
  const int t = threadIdx.x, l = t & 63, w = t >> 6;
  const int wr = w >> 1, wc = w & 1, l15 = l & 15, hi = l >> 4;
  const int gx = gridDim.x, gy = gridDim.y;
  const int nwg = gx * gy * gridDim.z;
  const int lin = blockIdx.x + gx * (blockIdx.y + gy * blockIdx.z);
  const int cpx = nwg >> 3;
  const int sw = (nwg & 7) ? lin : ((lin & 7) * cpx + (lin >> 3));
  const int ntile = sw % gx;
  const int rest = sw / gx;
  const int mtile = rest % gy, bz = rest / gy;
  const uint16_t* Ab = A + (size_t)bz * sA;
  const uint16_t* Bb = B + (size_t)bz * sB;
  uint16_t* Cb = C + (size_t)bz * sC;
  f32x4 acc[4][4];
  #pragma unroll
  for (int m = 0; m < 4; ++m)
    #pragma unroll
    for (int n = 0; n < 4; ++n) acc[m][n] = (f32x4){0.f, 0.f, 0.f, 0.f};
  const int srow = t >> 3, schunk = (t & 7) * 8;
  const int nk = K >> 6;
  for (int kt = 0; kt < nk; ++kt) {
    const int kb = kt << 6;
    #pragma unroll
    for (int i = 0; i < 4; ++i) {
      const int r = i * 32 + srow;
      gld16(&As[r * 64 + schunk], Ab + (size_t)(mtile * 128 + r) * lda + kb + schunk);
    }
    #pragma unroll
    for (int rd = 0; rd < 4; ++rd) {
      const int id = rd * 256 + t;
      const int kr = id >> 4;
      const int c = (id & 15) * 8;
      u16x8 gv = *(const u16x8*)(Bb + (size_t)(kb + kr) * ldb + ntile * 128 + c);
      #pragma unroll
      for (int j = 0; j < 8; ++j) Bt[(c + j) * 64 + kr] = gv[j];
    }
    __syncthreads();
    #pragma unroll
    for (int ks = 0; ks < 2; ++ks) {
      const int k0 = ks * 32 + hi * 8;
      bf16x8 a[4], bb[4];
      #pragma unroll
      for (int m = 0; m < 4; ++m) a[m] = *(const bf16x8*)&As[(wr * 64 + m * 16 + l15) * 64 + k0];
      #pragma unroll
      for (int n = 0; n < 4; ++n) bb[n] = *(const bf16x8*)&Bt[(wc * 64 + n * 16 + l15) * 64 + k0];
      #pragma unroll
      for (int m = 0; m < 4; ++m)
        #pragma unroll
        for (int n = 0; n < 4; ++n) acc[m][n] = MFMA16(a[m], bb[n], acc[m][n]);
    }
    __syncthreads();
  }
  #pragma unroll
  for (int m = 0; m < 4; ++m) {
    const int row = mtile * 128 + wr * 64 + m * 16 + hi * 4;
    #pragma unroll
    for (int n = 0; n < 4; ++n) {
      const int col = ntile * 128 + wc * 64 + n * 16 + l15;
      #pragma unroll
      for (int r = 0; r < 4; ++r)
        Cb[(size_t)(row + r) * ldc + col] = f2b(acc[m][n][r]);
    }
  }
}

// ---------------- Wg_h[e][d] = sum_o Wke_h[o][e]*Wqe_h[o][d] ; v_h[e] = sum_o Wke_h[o][e]*bqe_h[o]
__global__ __launch_bounds__(256) void gemm_atb_kernel(
    const uint16_t* __restrict__ Wke, const uint16_t* __restrict__ Wqe,
    const float* __restrict__ bqe, uint16_t* __restrict__ Wg,
    float* __restrict__ vh) {
  __shared__ uint16_t At[128 * 64];
  __shared__ uint16_t Bt[128 * 64];
  const int h = blockIdx.x;
  const int t = threadIdx.x, l = t & 63, w = t >> 6;
  const int wr = w >> 1, wc = w & 1, l15 = l & 15, hi = l >> 4;
  const uint16_t* A = Wke + (size_t)h * 16384;
  const uint16_t* B = Wqe + (size_t)h * 16384;
  f32x4 acc[4][4];
  #pragma unroll
  for (int m = 0; m < 4; ++m)
    #pragma unroll
    for (int n = 0; n < 4; ++n) acc[m][n] = (f32x4){0.f, 0.f, 0.f, 0.f};
  float vacc = 0.f;
  for (int kt = 0; kt < 2; ++kt) {
    const int kb = kt << 6;
    #pragma unroll
    for (int rd = 0; rd < 4; ++rd) {
      const int id = rd * 256 + t;
      const int kr = id >> 4;
      const int c = (id & 15) * 8;
      u16x8 ga = *(const u16x8*)(A + (size_t)(kb + kr) * 128 + c);
      u16x8 gb = *(const u16x8*)(B + (size_t)(kb + kr) * 128 + c);
      #pragma unroll
      for (int j = 0; j < 8; ++j) {
        const int row = c + j;
        const int sxz = (((row & 7) ^ ((row >> 3) & 7)) << 3);
        At[row * 64 + (kr ^ sxz)] = ga[j];
        Bt[row * 64 + (kr ^ sxz)] = gb[j];
      }
    }
    __syncthreads();
    if (t < 128) {
      const int sxz = (((t & 7) ^ ((t >> 3) & 7)) << 3);
      for (int o = 0; o < 64; ++o)
        vacc += b2f(At[t * 64 + (o ^ sxz)]) * bqe[h * 128 + kb + o];
    }
    #pragma unroll
    for (int ks = 0; ks < 2; ++ks) {
      bf16x8 a[4], bb[4];
      #pragma unroll
      for (int m = 0; m < 4; ++m) {
        const int mr = wr * 64 + m * 16 + l15;
        const int sxz = (((mr & 7) ^ ((mr >> 3) & 7)) << 3);
        a[m] = *(const bf16x8*)&At[mr * 64 + ((ks * 32 + hi * 8) ^ sxz)];
      }
      #pragma unroll
      for (int n = 0; n < 4; ++n) {
        const int nr = wc * 64 + n * 16 + l15;
        const int sxz = (((nr & 7) ^ ((nr >> 3) & 7)) << 3);
        bb[n] = *(const bf16x8*)&Bt[nr * 64 + ((ks * 32 + hi * 8) ^ sxz)];
      }
      #pragma unroll
      for (int m = 0; m < 4; ++m)
        #pragma unroll
        for (int n = 0; n < 4; ++n) acc[m][n] = MFMA16(a[m], bb[n], acc[m][n]);
    }
    __syncthreads();
  }
  if (t < 128) vh[h * 128 + t] = vacc;
  #pragma unroll
  for (int m = 0; m < 4; ++m) {
    const int row = wr * 64 + m * 16 + hi * 4;
    #pragma unroll
    for (int n = 0; n < 4; ++n) {
      const int col = wc * 64 + n * 16 + l15;
      #pragma unroll
      for (int r = 0; r < 4; ++r)
        Wg[(size_t)h * 16384 + (size_t)(row + r) * 128 + col] = f2b(acc[m][n][r]);
    }
  }
}

// ---------------- fused attention + PV (512 threads / 8 waves) ----------------------
__global__ __launch_bounds__(512) void att_fused(
    const uint16_t* __restrict__ xg, const uint16_t* __restrict__ Wg,
    const float* __restrict__ vh, const float* __restrict__ wts,
    const float* __restrict__ padsum, uint16_t* __restrict__ tout) {
  __shared__ uint16_t Xr[2][128 * 64];
  __shared__ uint16_t GP[2][128 * 64];
  __shared__ float bS[4][128];
  const int blk = blockIdx.x;
  const int b = (blk & 7) * 64 + (blk >> 3);
  const int t = threadIdx.x, l = t & 63, wband = t >> 6;
  const int l15 = l & 15, hi = l >> 4;
  const int srow = t >> 3;
  const int schunk = (t & 7) * 8;
  const int gchunk = (((t & 7) ^ (srow & 7)) * 8);
  const float SCALE = 0.088388347648318447f;
  const int rsw = (l15 & 7);

  const uint16_t* xb = xg + (size_t)b * 16384;
  #pragma unroll
  for (int kt = 0; kt < 2; ++kt)
    #pragma unroll
    for (int i = 0; i < 2; ++i) {
      const int r = i * 64 + srow;
      gld16(&Xr[kt][r * 64 + schunk], xb + (size_t)r * 128 + kt * 64 + gchunk);
      gld16(&GP[kt][r * 64 + schunk], Wg + (size_t)r * 128 + kt * 64 + gchunk);
    }
  asm volatile("s_waitcnt vmcnt(0)" ::: "memory");
  __builtin_amdgcn_s_barrier();
  {
    const int hh = t >> 7, j = t & 127;
    float s = 0.f;
    for (int e = 0; e < 128; ++e) {
      const int c = e & 63;
      const int addr = j * 64 + ((((c >> 3) ^ (j & 7)) << 3) | (c & 7));
      s += b2f(Xr[e >> 6][addr]) * vh[hh * 128 + e];
    }
    bS[hh][j] = s * SCALE +
                ((padsum[(size_t)b * 128 + j] == 0.f) ? -__builtin_inff() : 0.f);
  }

  f32x4 awacc[8];
  #pragma unroll
  for (int n = 0; n < 8; ++n) awacc[n] = (f32x4){0.f, 0.f, 0.f, 0.f};
  u16x8 wreg[4];
  u16x8 xtr[4];

  for (int h = 0; h < 4; ++h) {
    f32x4 pacc[8];
    #pragma unroll
    for (int n = 0; n < 8; ++n) pacc[n] = (f32x4){0.f, 0.f, 0.f, 0.f};
    __builtin_amdgcn_s_setprio(1);
    #pragma unroll
    for (int kt = 0; kt < 2; ++kt)
      #pragma unroll
      for (int ks = 0; ks < 2; ++ks) {
        const int gck = ((ks * 4 + hi) ^ rsw) * 8;
        bf16x8 a, bb[8];
        a = *(const bf16x8*)&Xr[kt][(wband * 16 + l15) * 64 + gck];
        #pragma unroll
        for (int n = 0; n < 8; ++n)
          bb[n] = *(const bf16x8*)&GP[kt][(n * 16 + l15) * 64 + gck];
        #pragma unroll
        for (int n = 0; n < 8; ++n) pacc[n] = MFMA16(a, bb[n], pacc[n]);
      }
    __builtin_amdgcn_s_setprio(0);
    if (h + 1 < 4) {
      #pragma unroll
      for (int kt = 0; kt < 2; ++kt)
        #pragma unroll
        for (int i = 0; i < 2; ++i) {
          const int r = i * 64 + srow;
          wreg[kt * 2 + i] = *(const u16x8*)(Wg + (size_t)(h + 1) * 16384 +
                                             (size_t)r * 128 + kt * 64 + gchunk);
        }
    }
    __builtin_amdgcn_s_barrier();
    #pragma unroll
    for (int n = 0; n < 8; ++n) {
      const int cl = n * 16 + l15;
      const int c = cl & 63;
      #pragma unroll
      for (int r = 0; r < 4; ++r) {
        const int rr = wband * 16 + hi * 4 + r;
        GP[cl >> 6][rr * 64 + ((((c >> 3) ^ (rr & 7)) << 3) | (c & 7))] =
            f2b(pacc[n][r]);
      }
    }
    __builtin_amdgcn_s_barrier();
    f32x4 sacc[8];
    #pragma unroll
    for (int n = 0; n < 8; ++n) sacc[n] = (f32x4){0.f, 0.f, 0.f, 0.f};
    __builtin_amdgcn_s_setprio(1);
    #pragma unroll
    for (int kt = 0; kt < 2; ++kt)
      #pragma unroll
      for (int ks = 0; ks < 2; ++ks) {
        const int gck = ((ks * 4 + hi) ^ rsw) * 8;
        bf16x8 a, bb[8];
        a = *(const bf16x8*)&GP[kt][(wband * 16 + l15) * 64 + gck];
        #pragma unroll
        for (int n = 0; n < 8; ++n)
          bb[n] = *(const bf16x8*)&Xr[kt][(n * 16 + l15) * 64 + gck];
        #pragma unroll
        for (int n = 0; n < 8; ++n) sacc[n] = MFMA16(a, bb[n], sacc[n]);
      }
    __builtin_amdgcn_s_setprio(0);
    if (h == 3) {
      #pragma unroll
      for (int i = 0; i < 4; ++i) {
        const int id = i * 512 + t;
        const int jr = id >> 4;
        const int cc = (id & 15) * 8;
        xtr[i] = *(const u16x8*)(xb + (size_t)jr * 128 + cc);
      }
    }
    #pragma unroll
    for (int r = 0; r < 4; ++r) {
      float e[8], z = 0.f;
      #pragma unroll
      for (int n = 0; n < 8; ++n) {
        e[n] = __expf(sacc[n][r] * SCALE + bS[h][n * 16 + l15]);
        z += e[n];
      }
      z += __shfl_xor(z, 1); z += __shfl_xor(z, 2);
      z += __shfl_xor(z, 4); z += __shfl_xor(z, 8);
      const float zi = 1.f / z;
      #pragma unroll
      for (int n = 0; n < 8; ++n) awacc[n][r] += e[n] * zi;
    }
    if (h + 1 < 4) {
      __builtin_amdgcn_s_barrier();
      asm volatile("s_waitcnt vmcnt(0)" ::: "memory");
      #pragma unroll
      for (int kt = 0; kt < 2; ++kt)
        #pragma unroll
        for (int i = 0; i < 2; ++i) {
          const int r = i * 64 + srow;
          *(u16x8*)&GP[kt][r * 64 + schunk] = wreg[kt * 2 + i];
        }
      __builtin_amdgcn_s_barrier();
    }
  }
  float wv[8];
  #pragma unroll
  for (int n = 0; n < 8; ++n) wv[n] = wts[(size_t)b * 128 + n * 16 + l15];
  __builtin_amdgcn_s_barrier();
  #pragma unroll
  for (int r = 0; r < 4; ++r) {
    float z = 0.f;
    #pragma unroll
    for (int n = 0; n < 8; ++n) z += awacc[n][r] * wv[n];
    z += __shfl_xor(z, 1); z += __shfl_xor(z, 2);
    z += __shfl_xor(z, 4); z += __shfl_xor(z, 8);
    const float zi = 1.f / z;
    const int rr = wband * 16 + hi * 4 + r;
    #pragma unroll
    for (int n = 0; n < 8; ++n) {
      const int cl = n * 16 + l15;
      const int c = cl & 63;
      GP[cl >> 6][rr * 64 + ((((c >> 3) ^ (rr & 7)) << 3) | (c & 7))] =
          f2b(awacc[n][r] * wv[n] * zi);
    }
  }
  asm volatile("s_waitcnt vmcnt(0)" ::: "memory");
  #pragma unroll
  for (int i = 0; i < 4; ++i) {
    const int id = i * 512 + t;
    const int jr = id >> 4;
    const int cc = (id & 15) * 8;
    const int kt2 = jr >> 6, kr = jr & 63;
    #pragma unroll
    for (int j = 0; j < 8; ++j) {
      const int drow = cc + j;
      const int sxz = (((drow & 7) ^ ((drow >> 3) & 7)) << 3);
      Xr[kt2][drow * 64 + (kr ^ sxz)] = xtr[i][j];
    }
  }
  __builtin_amdgcn_s_barrier();
  f32x4 tacc[8];
  #pragma unroll
  for (int n = 0; n < 8; ++n) tacc[n] = (f32x4){0.f, 0.f, 0.f, 0.f};
  __builtin_amdgcn_s_setprio(1);
  #pragma unroll
  for (int kt = 0; kt < 2; ++kt)
    #pragma unroll
    for (int ks = 0; ks < 2; ++ks) {
      const int gck = ((ks * 4 + hi) ^ rsw) * 8;
      bf16x8 a, bb[8];
      a = *(const bf16x8*)&GP[kt][(wband * 16 + l15) * 64 + gck];
      #pragma unroll
      for (int n = 0; n < 8; ++n) {
        const int nr = n * 16 + l15;
        const int sxz = (((nr & 7) ^ ((nr >> 3) & 7)) << 3);
        bb[n] = *(const bf16x8*)&Xr[kt][nr * 64 + ((ks * 32 + hi * 8) ^ sxz)];
      }
      #pragma unroll
      for (int n = 0; n < 8; ++n) tacc[n] = MFMA16(a, bb[n], tacc[n]);
    }
  __builtin_amdgcn_s_setprio(0);
  #pragma unroll
  for (int r = 0; r < 4; ++r) {
    const int row = wband * 16 + hi * 4 + r;
    #pragma unroll
    for (int n = 0; n < 8; ++n) {
      const int col = n * 16 + l15;
      tout[(size_t)b * 16384 + (size_t)row * 128 + col] = f2b(tacc[n][r]);
    }
  }
}

// =======================================================================================
extern "C" void kernel_launch(void* const* d_in, const int* in_sizes, int n_in,
                              void* d_out, int out_size, void* d_ws, size_t ws_size,
                              hipStream_t stream) {
  (void)in_sizes; (void)n_in; (void)out_size; (void)ws_size;
  const float* x     = (const float*)d_in[0];
  const float* wts   = (const float*)d_in[1];
  const float* emb_W = (const float*)d_in[2];
  const float* emb_b = (const float*)d_in[3];
  const float* wq_W  = (const float*)d_in[4];
  const float* wq_b  = (const float*)d_in[5];
  const float* wk_W  = (const float*)d_in[6];
  const float* wk_b  = (const float*)d_in[7];
  const float* wv_W  = (const float*)d_in[8];
  const float* wv_b  = (const float*)d_in[9];
  const float* ipW   = (const float*)d_in[10];
  const float* ipb   = (const float*)d_in[11];
  const float* ln_g  = (const float*)d_in[12];
  const float* ln_b  = (const float*)d_in[13];
  const float* out_W = (const float*)d_in[14];
  const float* out_b = (const float*)d_in[15];

  char* ws = (char*)d_ws;
  size_t off = 0;
  auto alloc = [&](size_t bytes) { void* p = ws + off; off += (bytes + 255) & ~(size_t)255; return p; };
  uint16_t* wqW_bf = (uint16_t*)alloc(524288);
  uint16_t* wkW_bf = (uint16_t*)alloc(524288);
  uint16_t* ip_bf  = (uint16_t*)alloc(1048576);
  uint16_t* owW_bf = (uint16_t*)alloc(131072);     // Wg2 = out_W * ln_g
  uint16_t* Wqc    = (uint16_t*)alloc(524288);     // contiguous Wqc,Wkc,Wvc
  uint16_t* Wkc    = (uint16_t*)alloc(524288);
  uint16_t* Wvc    = (uint16_t*)alloc(524288);
  uint16_t* embW2  = (uint16_t*)alloc(131072);     // contiguous embW2,Wqe,Wke,Wve
  uint16_t* Wqe    = (uint16_t*)alloc(131072);
  uint16_t* Wke    = (uint16_t*)alloc(131072);
  uint16_t* Wve    = (uint16_t*)alloc(131072);
  uint16_t* Wg     = (uint16_t*)alloc(131072);
  float*    vhbuf  = (float*)alloc(2048);
  float*    t1q    = (float*)alloc(2048);
  float*    t1k    = (float*)alloc(2048);
  float*    biasE  = (float*)alloc(2048);
  float*    bqe    = (float*)alloc(2048);
  float*    bke    = (float*)alloc(2048);
  float*    bve    = (float*)alloc(2048);
  float*    uarr   = (float*)alloc(2048);
  float*    varr   = (float*)alloc(2048);
  float*    pad    = (float*)alloc(262144);
  float*    ssum   = (float*)alloc(262144);
  float*    ssq    = (float*)alloc(262144);
  uint16_t* xe     = (uint16_t*)alloc(67108864);
  uint16_t* B1     = (uint16_t*)alloc(67108864);   // t
  uint16_t* B2     = (uint16_t*)alloc(67108864);   // hv

  uint16_t* x_bf = (uint16_t*)d_out + 8388608;     // d_out upper 16 MiB
  uint16_t* tb   = B1;
  uint16_t* hv   = B2;

  const int TB = 256;
  pack_all<<<9600, TB, 0, stream>>>(x, emb_W, wq_W, wk_W, wv_W, ipW, out_W, ln_g,
                                    x_bf, embW2, wqW_bf, wkW_bf, Wvc, ip_bf, owW_bf);
  bias_stage1<<<384, TB, 0, stream>>>(wq_W, wk_W, wv_W, emb_b, wq_b, wk_b, wv_b,
                                      t1q, t1k, bve, pad, biasE, ssum, ssq);
  bias_stage2<<<320, TB, 0, stream>>>(ipW, ipb, t1q, t1k, bqe, bke,
                                      out_W, ln_g, ln_b, out_b, uarr, varr);
  gemm_ab_kernel<<<dim3(4, 4, 2), TB, 0, stream>>>(ip_bf, 512, 262144, wqW_bf, 512, 262144,
                                                   Wqc, 512, 262144, 512);
  gemm_ab_kernel<<<dim3(1, 4, 3), TB, 0, stream>>>(Wqc, 512, 262144, embW2, 128, 0,
                                                   Wqe, 128, 65536, 512);
  gemm_atb_kernel<<<4, TB, 0, stream>>>(Wke, Wqe, bqe, Wg, vhbuf);
  // xe = x @ emb_W^T + emb_b (persistent W; 512-thread blocks, 16 waves/CU)
  gemm_btp_kernel<1, true, false><<<dim3(4, 128, 1), 512, 0, stream>>>(
      x_bf, 0, embW2, 0, biasE, 0, xe, 0, 4, pad, nullptr, nullptr, nullptr);
  // fused attention + PV -> t
  att_fused<<<512, 512, 0, stream>>>(x_bf, Wg, vhbuf, wts, pad, tb);
  // hv = xe + softplus(t @ Wve^T + bve); row stats accumulated via atomics
  gemm_btp_kernel<1, false, true><<<dim3(4, 128, 1), 512, 0, stream>>>(
      tb, 0, Wve, 0, bve, 0, hv, 0, 4, nullptr, xe, ssum, ssq);
  // out = LN-fold: rstd*(hv@Wg2^T - mu*u) + v, f32 -> d_out
  gemm_bt_kernel<float, 0, true><<<dim3(1, 512, 1), TB, 0, stream>>>(
      hv, 0, owW_bf, 0, nullptr, 0, (float*)d_out, 0, 128, 512,
      ssum, ssq, uarr, varr);
}

// Round 31
// 213.320 us; speedup vs baseline: 1.2922x; 1.0044x over previous
//
#include <hip/hip_runtime.h>
#include <stdint.h>

// Shapes (fixed): B=512, N=128, E=128, H=4, D=512, hd=128.

typedef __attribute__((ext_vector_type(8))) __bf16 bf16x8;
typedef __attribute__((ext_vector_type(8))) uint16_t u16x8;
typedef __attribute__((ext_vector_type(4))) float f32x4;

__device__ __forceinline__ float b2f(uint16_t h) {
  union { uint32_t u; float f; } c; c.u = ((uint32_t)h) << 16; return c.f;
}
__device__ __forceinline__ uint16_t f2b(float f) {
  __bf16 h = (__bf16)f;
  union { __bf16 b; uint16_t u; } c; c.b = h; return c.u;
}
__device__ __forceinline__ void gld16(void* lds, const void* g) {
  __builtin_amdgcn_global_load_lds(
      (const __attribute__((address_space(1))) uint32_t*)(g),
      (__attribute__((address_space(3))) uint32_t*)(lds),
      16, 0, 0);
}

#define MFMA16(a, b, c) __builtin_amdgcn_mfma_f32_16x16x32_bf16((a), (b), (c), 0, 0, 0)

// ---------------- merged pack: x + all weights (out_W scaled by ln_g -> Wg2) ----------
__global__ __launch_bounds__(256) void pack_all(
    const float* __restrict__ x,
    const float* __restrict__ emb_W, const float* __restrict__ wq_W,
    const float* __restrict__ wk_W, const float* __restrict__ wv_W,
    const float* __restrict__ ipW, const float* __restrict__ out_W,
    const float* __restrict__ ln_g,
    uint16_t* __restrict__ x_bf,
    uint16_t* __restrict__ embW2, uint16_t* __restrict__ wqW_bf,
    uint16_t* __restrict__ wkW_bf, uint16_t* __restrict__ Wvc,
    uint16_t* __restrict__ ip_bf, uint16_t* __restrict__ owW_bf) {
  int i = blockIdx.x * 256 + threadIdx.x;
  if (i < 2097152) {
    float4 v = ((const float4*)x)[i];
    ushort4 o;
    o.x = f2b(v.x); o.y = f2b(v.y); o.z = f2b(v.z); o.w = f2b(v.w);
    ((ushort4*)x_bf)[i] = o;
    return;
  }
  int i2 = i - 2097152;
  if (i2 >= 360448) return;
  if (i2 >= 344064) {  // out_W scaled by ln_g -> Wg2
    const int off = i2 - 344064;
    float4 v = ((const float4*)out_W)[off];
    const int base = off * 4;
    ushort4 o;
    o.x = f2b(v.x * ln_g[(base + 0) & 511]);
    o.y = f2b(v.y * ln_g[(base + 1) & 511]);
    o.z = f2b(v.z * ln_g[(base + 2) & 511]);
    o.w = f2b(v.w * ln_g[(base + 3) & 511]);
    ((ushort4*)owW_bf)[off] = o;
    return;
  }
  const float* src; uint16_t* dst; int off;
  if (i2 < 16384)       { src = emb_W; dst = embW2;  off = i2; }
  else if (i2 < 81920)  { src = wq_W;  dst = wqW_bf; off = i2 - 16384; }
  else if (i2 < 147456) { src = wk_W;  dst = wkW_bf; off = i2 - 81920; }
  else if (i2 < 212992) { src = wv_W;  dst = Wvc;    off = i2 - 147456; }
  else                  { src = ipW;   dst = ip_bf;  off = i2 - 212992; }
  float4 v = ((const float4*)src)[off];
  ushort4 o;
  o.x = f2b(v.x); o.y = f2b(v.y); o.z = f2b(v.z); o.w = f2b(v.w);
  ((ushort4*)dst)[off] = o;
}

// ---------------- fused bias folds + zero-init (pad, stats) + emb_b copy ----------------
__global__ __launch_bounds__(256) void bias_stage1(
    const float* __restrict__ wq_W, const float* __restrict__ wk_W,
    const float* __restrict__ wv_W, const float* __restrict__ emb_b,
    const float* __restrict__ wq_b, const float* __restrict__ wk_b,
    const float* __restrict__ wv_b,
    float* __restrict__ t1q, float* __restrict__ t1k, float* __restrict__ bve,
    float* __restrict__ pad_init, float* __restrict__ biasE,
    float* __restrict__ ssum, float* __restrict__ ssq) {
  const int gid = blockIdx.x * 256 + threadIdx.x;
  if (gid < 65536) { pad_init[gid] = 0.f; ssum[gid] = 0.f; ssq[gid] = 0.f; }
  if (gid < 512) biasE[gid] = emb_b[gid];
  const int t = threadIdx.x, l = t & 63, w = t >> 6;
  const int sel = blockIdx.x >> 7;
  const int row = (blockIdx.x & 127) * 4 + w;
  const float* Wbig = sel == 0 ? wq_W : (sel == 1 ? wk_W : wv_W);
  const float* b2   = sel == 0 ? wq_b : (sel == 1 ? wk_b : wv_b);
  float* out        = sel == 0 ? t1q  : (sel == 1 ? t1k  : bve);
  float s = 0.f;
  #pragma unroll
  for (int j = 0; j < 8; ++j) {
    int c = j * 64 + l;
    s += Wbig[(size_t)row * 512 + c] * emb_b[c];
  }
  #pragma unroll
  for (int m = 1; m < 64; m <<= 1) s += __shfl_xor(s, m);
  if (l == 0) out[row] = s + b2[row];
}

__global__ __launch_bounds__(256) void bias_stage2(
    const float* __restrict__ ipW, const float* __restrict__ ipb,
    const float* __restrict__ t1q, const float* __restrict__ t1k,
    float* __restrict__ bqe, float* __restrict__ bke,
    const float* __restrict__ out_W, const float* __restrict__ ln_g,
    const float* __restrict__ ln_b, const float* __restrict__ out_b,
    float* __restrict__ u, float* __restrict__ v) {
  const int t = threadIdx.x, l = t & 63, w = t >> 6;
  const int blk = blockIdx.x;
  if (blk < 256) {
    const int sel = blk >> 7;
    const int row = (blk & 127) * 4 + w;
    const float* Wbig = ipW + (size_t)sel * 262144;
    const float* b1   = sel == 0 ? t1q : t1k;
    const float* b2   = ipb + sel * 512;
    float* out        = sel == 0 ? bqe : bke;
    float s = 0.f;
    #pragma unroll
    for (int j = 0; j < 8; ++j) {
      int c = j * 64 + l;
      s += Wbig[(size_t)row * 512 + c] * b1[c];
    }
    #pragma unroll
    for (int m = 1; m < 64; m <<= 1) s += __shfl_xor(s, m);
    if (l == 0) out[row] = s + b2[row];
  } else {
    const int r4 = (blk - 256) * 4 + w;  // 0..255
    const int row = r4 & 127;
    const float* src = (r4 < 128) ? ln_g : ln_b;
    float s = 0.f;
    #pragma unroll
    for (int j = 0; j < 8; ++j) {
      int c = j * 64 + l;
      s += out_W[(size_t)row * 512 + c] * src[c];
    }
    #pragma unroll
    for (int m = 1; m < 64; m <<= 1) s += __shfl_xor(s, m);
    if (l == 0) {
      if (r4 < 128) u[row] = s;
      else v[row] = s + out_b[row];
    }
  }
}

// ---------------- persistent-W GEMM: C(Mx512) = A(Mx128) @ W(512x128)^T + bias --------
// 512 threads / 8 waves per block, SAME 128x128 tile + 64KB LDS -> 16 waves/CU.
// Each wave: 32x64 sub-tile, acc[2][4]. Staging: 2 gld16/thread (vmcnt 2).
// Transposed MFMA epilogue: lane row=..+l15, cols=..+hi*4+r, vector stores.
template <int BIAS_MODE, bool PAD_ACC, bool HV>
__global__ __launch_bounds__(512, 4) void gemm_btp_kernel(
    const uint16_t* __restrict__ A, long long sA,
    const uint16_t* __restrict__ W, long long sW,
    const float* __restrict__ bias, long long sBias,
    uint16_t* __restrict__ C, long long sC,
    int mIter, float* __restrict__ padout,
    const uint16_t* __restrict__ xein, float* __restrict__ ssum,
    float* __restrict__ ssq) {
  __shared__ uint16_t Ws[2][128 * 64];
  __shared__ uint16_t As[2][128 * 64];
  const int t = threadIdx.x, l = t & 63, w = t >> 6;   // w in [0,8)
  const int wr = w >> 1, wc = w & 1, l15 = l & 15, hi = l >> 4;
  const int gx = gridDim.x, gy = gridDim.y;
  const int nwg = gx * gy * gridDim.z;
  const int lin = blockIdx.x + gx * (blockIdx.y + gy * blockIdx.z);
  const int cpx = nwg >> 3;
  const int sw = (nwg & 7) ? lin : ((lin & 7) * cpx + (lin >> 3));
  const int ntile = sw % gx;
  const int rest = sw / gx;
  const int mg = rest % gy, bz = rest / gy;
  const uint16_t* Ab = A + (size_t)bz * sA;
  const uint16_t* Wb = W + (size_t)bz * sW;
  uint16_t* Cb = C + (size_t)bz * sC;
  const float* biasb = bias + (size_t)bz * sBias;
  const int srow = t >> 3;            // [0,64)
  const int schunk = (t & 7) * 8;
  const int gchunk = (((t & 7) ^ (srow & 7)) * 8);
  const int rowB0 = ntile * 128;
  #pragma unroll
  for (int kt = 0; kt < 2; ++kt)
    #pragma unroll
    for (int i = 0; i < 2; ++i) {
      const int r = i * 64 + srow;
      gld16(&Ws[kt][r * 64 + schunk], Wb + (size_t)(rowB0 + r) * 128 + kt * 64 + gchunk);
    }
  auto stageA = [&](int u) {
    const int rowA0 = (mg * mIter + (u >> 1)) * 128;
    const int kb = (u & 1) << 6;
    #pragma unroll
    for (int i = 0; i < 2; ++i) {
      const int r = i * 64 + srow;
      gld16(&As[u & 1][r * 64 + schunk], Ab + (size_t)(rowA0 + r) * 128 + kb + gchunk);
    }
  };
  const int rsw = (l15 & 7);
  stageA(0);
  const int U = mIter * 2;
  f32x4 acc[2][4];
  for (int u = 0; u < U; ++u) {
    const int kt = u & 1;
    if (kt == 0) {
      #pragma unroll
      for (int m = 0; m < 2; ++m)
        #pragma unroll
        for (int n = 0; n < 4; ++n) acc[m][n] = (f32x4){0.f, 0.f, 0.f, 0.f};
    }
    if (u + 1 < U) {
      stageA(u + 1);
      asm volatile("s_waitcnt vmcnt(2)" ::: "memory");
    } else {
      asm volatile("s_waitcnt vmcnt(0)" ::: "memory");
    }
    __builtin_amdgcn_s_barrier();
    asm volatile("" ::: "memory");
    #pragma unroll
    for (int ks = 0; ks < 2; ++ks) {
      const int gck = ((ks * 4 + hi) ^ rsw) * 8;
      bf16x8 a[2], bb[4];
      #pragma unroll
      for (int m = 0; m < 2; ++m)
        a[m] = *(const bf16x8*)&As[kt][(wr * 32 + m * 16 + l15) * 64 + gck];
      #pragma unroll
      for (int n = 0; n < 4; ++n)
        bb[n] = *(const bf16x8*)&Ws[kt][(wc * 64 + n * 16 + l15) * 64 + gck];
      // swapped operands -> transposed fragment: lane row = l15, cols = hi*4+r
      #pragma unroll
      for (int m = 0; m < 2; ++m)
        #pragma unroll
        for (int n = 0; n < 4; ++n) acc[m][n] = MFMA16(bb[n], a[m], acc[m][n]);
    }
    asm volatile("" ::: "memory");
    __builtin_amdgcn_s_barrier();
    if (kt == 1) {
      const int rowA0 = (mg * mIter + (u >> 1)) * 128;
      #pragma unroll
      for (int m = 0; m < 2; ++m) {
        const int row = rowA0 + wr * 32 + m * 16 + l15;
        float padp = 0.f, hs = 0.f, hq = 0.f;
        #pragma unroll
        for (int n = 0; n < 4; ++n) {
          const int colb = rowB0 + wc * 64 + n * 16 + hi * 4;
          union { ushort4 v; uint16_t e[4]; } o, xv;
          if constexpr (HV)
            xv.v = *(const ushort4*)&xein[(size_t)row * 512 + colb];
          #pragma unroll
          for (int r = 0; r < 4; ++r) {
            float rv = acc[m][n][r];
            if constexpr (BIAS_MODE == 1) rv += biasb[colb + r];
            if constexpr (PAD_ACC) padp += fabsf(rv);
            if constexpr (HV) {
              const float sp = fmaxf(rv, 0.f) + __logf(1.f + __expf(-fabsf(rv)));
              const float hvv = b2f(xv.e[r]) + sp;
              hs += hvv;
              hq += hvv * hvv;
              o.e[r] = f2b(hvv);
            } else {
              o.e[r] = f2b(rv);
            }
          }
          *(ushort4*)&Cb[(size_t)row * 512 + colb] = o.v;
        }
        if constexpr (PAD_ACC) {
          if (bz == 0) {
            padp += __shfl_xor(padp, 16);
            padp += __shfl_xor(padp, 32);
            if (l < 16) atomicAdd(padout + row, padp);
          }
        }
        if constexpr (HV) {
          hs += __shfl_xor(hs, 16); hs += __shfl_xor(hs, 32);
          hq += __shfl_xor(hq, 16); hq += __shfl_xor(hq, 32);
          if (l < 16) {
            atomicAdd(ssum + row, hs);
            atomicAdd(ssq + row, hq);
          }
        }
      }
    }
  }
}

// ---------------- generic C(MxN) = A(MxK) @ W(NxK)^T (final GEMM; LN fold) ----
// 512 threads / 8 waves, same 128x128 tile + 64KB LDS -> 16 waves/CU (R30 transform).
// Each wave: 32x64 sub-tile, acc[2][4]; stage = 4 gld16/thread, steady vmcnt(4).
template <typename OT, int BIAS_MODE, bool LN>
__global__ __launch_bounds__(512, 4) void gemm_bt_kernel(
    const uint16_t* __restrict__ A, long long sA,
    const uint16_t* __restrict__ W, long long sW,
    const float* __restrict__ bias, long long sBias,
    OT* __restrict__ C, long long sC, int N, int K,
    const float* __restrict__ ssum, const float* __restrict__ ssq,
    const float* __restrict__ uarr, const float* __restrict__ varr) {
  __shared__ uint16_t As[2][128 * 64];
  __shared__ uint16_t Bs[2][128 * 64];
  const int t = threadIdx.x, l = t & 63, w = t >> 6;   // w in [0,8)
  const int wr = w >> 1, wc = w & 1, l15 = l & 15, hi = l >> 4;
  const int gx = gridDim.x, gy = gridDim.y;
  const int nwg = gx * gy * gridDim.z;
  const int lin = blockIdx.x + gx * (blockIdx.y + gy * blockIdx.z);
  const int cpx = nwg >> 3;
  const int sw = (nwg & 7) ? lin : ((lin & 7) * cpx + (lin >> 3));
  const int ntile = sw % gx;
  const int rest = sw / gx;
  const int mtile = rest % gy, bz = rest / gy;
  const uint16_t* Ab = A + (size_t)bz * sA;
  const uint16_t* Wb = W + (size_t)bz * sW;
  OT* Cb = C + (size_t)bz * sC;
  const float* biasb = bias + (size_t)bz * sBias;
  f32x4 acc[2][4];
  #pragma unroll
  for (int m = 0; m < 2; ++m)
    #pragma unroll
    for (int n = 0; n < 4; ++n) acc[m][n] = (f32x4){0.f, 0.f, 0.f, 0.f};
  const int srow = t >> 3;            // [0,64)
  const int schunk = (t & 7) * 8;
  const int gchunk = (((t & 7) ^ (srow & 7)) * 8);
  const int nk = K >> 6;
  const int rowA0 = mtile * 128, rowB0 = ntile * 128;
  auto stage = [&](int kt, int buf) {
    const int kb = kt << 6;
    #pragma unroll
    for (int i = 0; i < 2; ++i) {
      const int r = i * 64 + srow;
      gld16(&As[buf][r * 64 + schunk], Ab + (size_t)(rowA0 + r) * K + kb + gchunk);
      gld16(&Bs[buf][r * 64 + schunk], Wb + (size_t)(rowB0 + r) * K + kb + gchunk);
    }
  };
  stage(0, 0);
  const int rsw = (l15 & 7);
  for (int kt = 0; kt < nk; ++kt) {
    const int cur = kt & 1;
    if (kt + 1 < nk) {
      stage(kt + 1, cur ^ 1);
      asm volatile("s_waitcnt vmcnt(4)" ::: "memory");
    } else {
      asm volatile("s_waitcnt vmcnt(0)" ::: "memory");
    }
    __builtin_amdgcn_s_barrier();
    asm volatile("" ::: "memory");
    #pragma unroll
    for (int ks = 0; ks < 2; ++ks) {
      const int gck = ((ks * 4 + hi) ^ rsw) * 8;
      bf16x8 a[2], bb[4];
      #pragma unroll
      for (int m = 0; m < 2; ++m)
        a[m] = *(const bf16x8*)&As[cur][(wr * 32 + m * 16 + l15) * 64 + gck];
      #pragma unroll
      for (int n = 0; n < 4; ++n)
        bb[n] = *(const bf16x8*)&Bs[cur][(wc * 64 + n * 16 + l15) * 64 + gck];
      // swapped operands -> transposed fragment
      #pragma unroll
      for (int m = 0; m < 2; ++m)
        #pragma unroll
        for (int n = 0; n < 4; ++n) acc[m][n] = MFMA16(bb[n], a[m], acc[m][n]);
    }
    asm volatile("" ::: "memory");
    __builtin_amdgcn_s_barrier();
  }
  #pragma unroll
  for (int m = 0; m < 2; ++m) {
    const int row = rowA0 + wr * 32 + m * 16 + l15;
    float mu = 0.f, rstd = 0.f;
    if constexpr (LN) {
      mu = ssum[row] * (1.f / 512.f);
      const float var = ssq[row] * (1.f / 512.f) - mu * mu;
      rstd = rsqrtf(var + 1e-5f);
    }
    #pragma unroll
    for (int n = 0; n < 4; ++n) {
      const int colb = rowB0 + wc * 64 + n * 16 + hi * 4;
      if constexpr (sizeof(OT) == 2) {
        union { ushort4 v; uint16_t e[4]; } o;
        #pragma unroll
        for (int r = 0; r < 4; ++r) {
          float rv;
          if constexpr (LN) {
            rv = rstd * (acc[m][n][r] - mu * uarr[colb + r]) + varr[colb + r];
          } else {
            float bv = 0.f;
            if constexpr (BIAS_MODE == 1) bv = biasb[colb + r];
            rv = acc[m][n][r] + bv;
          }
          o.e[r] = f2b(rv);
        }
        *(ushort4*)&((uint16_t*)Cb)[(size_t)row * N + colb] = o.v;
      } else {
        union { float4 v; float e[4]; } o;
        #pragma unroll
        for (int r = 0; r < 4; ++r) {
          float rv;
          if constexpr (LN) {
            rv = rstd * (acc[m][n][r] - mu * uarr[colb + r]) + varr[colb + r];
          } else {
            float bv = 0.f;
            if constexpr (BIAS_MODE == 1) bv = biasb[colb + r];
            rv = acc[m][n][r] + bv;
          }
          o.e[r] = rv;
        }
        *(float4*)&Cb[(size_t)row * N + colb] = o.v;
      }
    }
  }
}

// ---------------- C = A(MxK) @ B(KxN), B row-major (weight prep only) ----
__global__ __launch_bounds__(256) void gemm_ab_kernel(
    const uint16_t* __restrict__ A, int lda, long long sA,
    const uint16_t* __restrict__ B, int ldb, long long sB,
    uint16_t* __restrict__ C, int ldc, long long sC, int K) {
  __shared__ uint16_t As[128 * 64];
  __shared__ uint16_t Bt[128 * 64];
  const int t = threadIdx.x, l = t & 63, w = t >> 6;
  const int wr = w >> 1, wc = w & 1, l15 = l & 15, hi = l >> 4;
  const int gx = gridDim.x, gy = gridDim.y;
  const int nwg = gx * gy * gridDim.z;
  const int lin = blockIdx.x + gx * (blockIdx.y + gy * blockIdx.z);
  const int cpx = nwg >> 3;
  const int sw = (nwg & 7) ? lin : ((lin & 7) * cpx + (lin >> 3));
  const int ntile = sw % gx;
  const int rest = sw / gx;
  const int mtile = rest % gy, bz = rest / gy;
  const uint16_t* Ab = A + (size_t)bz * sA;
  const uint16_t* Bb = B + (size_t)bz * sB;
  uint16_t* Cb = C + (size_t)bz * sC;
  f32x4 acc[4][4];
  #pragma unroll
  for (int m = 0; m < 4; ++m)
    #pragma unroll
    for (int n = 0; n < 4; ++n) acc[m][n] = (f32x4){0.f, 0.f, 0.f, 0.f};
  const int srow = t >> 3, schunk = (t & 7) * 8;
  const int nk = K >> 6;
  for (int kt = 0; kt < nk; ++kt) {
    const int kb = kt << 6;
    #pragma unroll
    for (int i = 0; i < 4; ++i) {
      const int r = i * 32 + srow;
      gld16(&As[r * 64 + schunk], Ab + (size_t)(mtile * 128 + r) * lda + kb + schunk);
    }
    #pragma unroll
    for (int rd = 0; rd < 4; ++rd) {
      const int id = rd * 256 + t;
      const int kr = id >> 4;
      const int c = (id & 15) * 8;
      u16x8 gv = *(const u16x8*)(Bb + (size_t)(kb + kr) * ldb + ntile * 128 + c);
      #pragma unroll
      for (int j = 0; j < 8; ++j) Bt[(c + j) * 64 + kr] = gv[j];
    }
    __syncthreads();
    #pragma unroll
    for (int ks = 0; ks < 2; ++ks) {
      const int k0 = ks * 32 + hi * 8;
      bf16x8 a[4], bb[4];
      #pragma unroll
      for (int m = 0; m < 4; ++m) a[m] = *(const bf16x8*)&As[(wr * 64 + m * 16 + l15) * 64 + k0];
      #pragma unroll
      for (int n = 0; n < 4; ++n) bb[n] = *(const bf16x8*)&Bt[(wc * 64 + n * 16 + l15) * 64 + k0];
      #pragma unroll
      for (int m = 0; m < 4; ++m)
        #pragma unroll
        for (int n = 0; n < 4; ++n) acc[m][n] = MFMA16(a[m], bb[n], acc[m][n]);
    }
    __syncthreads();
  }
  #pragma unroll
  for (int m = 0; m < 4; ++m) {
    const int row = mtile * 128 + wr * 64 + m * 16 + hi * 4;
    #pragma unroll
    for (int n = 0; n < 4; ++n) {
      const int col = ntile * 128 + wc * 64 + n * 16 + l15;
      #pragma unroll
      for (int r = 0; r < 4; ++r)
        Cb[(size_t)(row + r) * ldc + col] = f2b(acc[m][n][r]);
    }
  }
}

// ---------------- Wg_h[e][d] = sum_o Wke_h[o][e]*Wqe_h[o][d] ; v_h[e] = sum_o Wke_h[o][e]*bqe_h[o]
__global__ __launch_bounds__(256) void gemm_atb_kernel(
    const uint16_t* __restrict__ Wke, const uint16_t* __restrict__ Wqe,
    const float* __restrict__ bqe, uint16_t* __restrict__ Wg,
    float* __restrict__ vh) {
  __shared__ uint16_t At[128 * 64];
  __shared__ uint16_t Bt[128 * 64];
  const int h = blockIdx.x;
  const int t = threadIdx.x, l = t & 63, w = t >> 6;
  const int wr = w >> 1, wc = w & 1, l15 = l & 15, hi = l >> 4;
  const uint16_t* A = Wke + (size_t)h * 16384;
  const uint16_t* B = Wqe + (size_t)h * 16384;
  f32x4 acc[4][4];
  #pragma unroll
  for (int m = 0; m < 4; ++m)
    #pragma unroll
    for (int n = 0; n < 4; ++n) acc[m][n] = (f32x4){0.f, 0.f, 0.f, 0.f};
  float vacc = 0.f;
  for (int kt = 0; kt < 2; ++kt) {
    const int kb = kt << 6;
    #pragma unroll
    for (int rd = 0; rd < 4; ++rd) {
      const int id = rd * 256 + t;
      const int kr = id >> 4;
      const int c = (id & 15) * 8;
      u16x8 ga = *(const u16x8*)(A + (size_t)(kb + kr) * 128 + c);
      u16x8 gb = *(const u16x8*)(B + (size_t)(kb + kr) * 128 + c);
      #pragma unroll
      for (int j = 0; j < 8; ++j) {
        const int row = c + j;
        const int sxz = (((row & 7) ^ ((row >> 3) & 7)) << 3);
        At[row * 64 + (kr ^ sxz)] = ga[j];
        Bt[row * 64 + (kr ^ sxz)] = gb[j];
      }
    }
    __syncthreads();
    if (t < 128) {
      const int sxz = (((t & 7) ^ ((t >> 3) & 7)) << 3);
      for (int o = 0; o < 64; ++o)
        vacc += b2f(At[t * 64 + (o ^ sxz)]) * bqe[h * 128 + kb + o];
    }
    #pragma unroll
    for (int ks = 0; ks < 2; ++ks) {
      bf16x8 a[4], bb[4];
      #pragma unroll
      for (int m = 0; m < 4; ++m) {
        const int mr = wr * 64 + m * 16 + l15;
        const int sxz = (((mr & 7) ^ ((mr >> 3) & 7)) << 3);
        a[m] = *(const bf16x8*)&At[mr * 64 + ((ks * 32 + hi * 8) ^ sxz)];
      }
      #pragma unroll
      for (int n = 0; n < 4; ++n) {
        const int nr = wc * 64 + n * 16 + l15;
        const int sxz = (((nr & 7) ^ ((nr >> 3) & 7)) << 3);
        bb[n] = *(const bf16x8*)&Bt[nr * 64 + ((ks * 32 + hi * 8) ^ sxz)];
      }
      #pragma unroll
      for (int m = 0; m < 4; ++m)
        #pragma unroll
        for (int n = 0; n < 4; ++n) acc[m][n] = MFMA16(a[m], bb[n], acc[m][n]);
    }
    __syncthreads();
  }
  if (t < 128) vh[h * 128 + t] = vacc;
  #pragma unroll
  for (int m = 0; m < 4; ++m) {
    const int row = wr * 64 + m * 16 + hi * 4;
    #pragma unroll
    for (int n = 0; n < 4; ++n) {
      const int col = wc * 64 + n * 16 + l15;
      #pragma unroll
      for (int r = 0; r < 4; ++r)
        Wg[(size_t)h * 16384 + (size_t)(row + r) * 128 + col] = f2b(acc[m][n][r]);
    }
  }
}

// ---------------- fused attention + PV (512 threads / 8 waves) ----------------------
__global__ __launch_bounds__(512) void att_fused(
    const uint16_t* __restrict__ xg, const uint16_t* __restrict__ Wg,
    const float* __restrict__ vh, const float* __restrict__ wts,
    const float* __restrict__ padsum, uint16_t* __restrict__ tout) {
  __shared__ uint16_t Xr[2][128 * 64];
  __shared__ uint16_t GP[2][128 * 64];
  __shared__ float bS[4][128];
  const int blk = blockIdx.x;
  const int b = (blk & 7) * 64 + (blk >> 3);
  const int t = threadIdx.x, l = t & 63, wband = t >> 6;
  const int l15 = l & 15, hi = l >> 4;
  const int srow = t >> 3;
  const int schunk = (t & 7) * 8;
  const int gchunk = (((t & 7) ^ (srow & 7)) * 8);
  const float SCALE = 0.088388347648318447f;
  const int rsw = (l15 & 7);

  const uint16_t* xb = xg + (size_t)b * 16384;
  #pragma unroll
  for (int kt = 0; kt < 2; ++kt)
    #pragma unroll
    for (int i = 0; i < 2; ++i) {
      const int r = i * 64 + srow;
      gld16(&Xr[kt][r * 64 + schunk], xb + (size_t)r * 128 + kt * 64 + gchunk);
      gld16(&GP[kt][r * 64 + schunk], Wg + (size_t)r * 128 + kt * 64 + gchunk);
    }
  asm volatile("s_waitcnt vmcnt(0)" ::: "memory");
  __builtin_amdgcn_s_barrier();
  {
    const int hh = t >> 7, j = t & 127;
    float s = 0.f;
    for (int e = 0; e < 128; ++e) {
      const int c = e & 63;
      const int addr = j * 64 + ((((c >> 3) ^ (j & 7)) << 3) | (c & 7));
      s += b2f(Xr[e >> 6][addr]) * vh[hh * 128 + e];
    }
    bS[hh][j] = s * SCALE +
                ((padsum[(size_t)b * 128 + j] == 0.f) ? -__builtin_inff() : 0.f);
  }

  f32x4 awacc[8];
  #pragma unroll
  for (int n = 0; n < 8; ++n) awacc[n] = (f32x4){0.f, 0.f, 0.f, 0.f};
  u16x8 wreg[4];
  u16x8 xtr[4];

  for (int h = 0; h < 4; ++h) {
    f32x4 pacc[8];
    #pragma unroll
    for (int n = 0; n < 8; ++n) pacc[n] = (f32x4){0.f, 0.f, 0.f, 0.f};
    __builtin_amdgcn_s_setprio(1);
    #pragma unroll
    for (int kt = 0; kt < 2; ++kt)
      #pragma unroll
      for (int ks = 0; ks < 2; ++ks) {
        const int gck = ((ks * 4 + hi) ^ rsw) * 8;
        bf16x8 a, bb[8];
        a = *(const bf16x8*)&Xr[kt][(wband * 16 + l15) * 64 + gck];
        #pragma unroll
        for (int n = 0; n < 8; ++n)
          bb[n] = *(const bf16x8*)&GP[kt][(n * 16 + l15) * 64 + gck];
        #pragma unroll
        for (int n = 0; n < 8; ++n) pacc[n] = MFMA16(a, bb[n], pacc[n]);
      }
    __builtin_amdgcn_s_setprio(0);
    if (h + 1 < 4) {
      #pragma unroll
      for (int kt = 0; kt < 2; ++kt)
        #pragma unroll
        for (int i = 0; i < 2; ++i) {
          const int r = i * 64 + srow;
          wreg[kt * 2 + i] = *(const u16x8*)(Wg + (size_t)(h + 1) * 16384 +
                                             (size_t)r * 128 + kt * 64 + gchunk);
        }
    }
    __builtin_amdgcn_s_barrier();
    #pragma unroll
    for (int n = 0; n < 8; ++n) {
      const int cl = n * 16 + l15;
      const int c = cl & 63;
      #pragma unroll
      for (int r = 0; r < 4; ++r) {
        const int rr = wband * 16 + hi * 4 + r;
        GP[cl >> 6][rr * 64 + ((((c >> 3) ^ (rr & 7)) << 3) | (c & 7))] =
            f2b(pacc[n][r]);
      }
    }
    __builtin_amdgcn_s_barrier();
    f32x4 sacc[8];
    #pragma unroll
    for (int n = 0; n < 8; ++n) sacc[n] = (f32x4){0.f, 0.f, 0.f, 0.f};
    __builtin_amdgcn_s_setprio(1);
    #pragma unroll
    for (int kt = 0; kt < 2; ++kt)
      #pragma unroll
      for (int ks = 0; ks < 2; ++ks) {
        const int gck = ((ks * 4 + hi) ^ rsw) * 8;
        bf16x8 a, bb[8];
        a = *(const bf16x8*)&GP[kt][(wband * 16 + l15) * 64 + gck];
        #pragma unroll
        for (int n = 0; n < 8; ++n)
          bb[n] = *(const bf16x8*)&Xr[kt][(n * 16 + l15) * 64 + gck];
        #pragma unroll
        for (int n = 0; n < 8; ++n) sacc[n] = MFMA16(a, bb[n], sacc[n]);
      }
    __builtin_amdgcn_s_setprio(0);
    if (h == 3) {
      #pragma unroll
      for (int i = 0; i < 4; ++i) {
        const int id = i * 512 + t;
        const int jr = id >> 4;
        const int cc = (id & 15) * 8;
        xtr[i] = *(const u16x8*)(xb + (size_t)jr * 128 + cc);
      }
    }
    #pragma unroll
    for (int r = 0; r < 4; ++r) {
      float e[8], z = 0.f;
      #pragma unroll
      for (int n = 0; n < 8; ++n) {
        e[n] = __expf(sacc[n][r] * SCALE + bS[h][n * 16 + l15]);
        z += e[n];
      }
      z += __shfl_xor(z, 1); z += __shfl_xor(z, 2);
      z += __shfl_xor(z, 4); z += __shfl_xor(z, 8);
      const float zi = 1.f / z;
      #pragma unroll
      for (int n = 0; n < 8; ++n) awacc[n][r] += e[n] * zi;
    }
    if (h + 1 < 4) {
      __builtin_amdgcn_s_barrier();
      asm volatile("s_waitcnt vmcnt(0)" ::: "memory");
      #pragma unroll
      for (int kt = 0; kt < 2; ++kt)
        #pragma unroll
        for (int i = 0; i < 2; ++i) {
          const int r = i * 64 + srow;
          *(u16x8*)&GP[kt][r * 64 + schunk] = wreg[kt * 2 + i];
        }
      __builtin_amdgcn_s_barrier();
    }
  }
  float wv[8];
  #pragma unroll
  for (int n = 0; n < 8; ++n) wv[n] = wts[(size_t)b * 128 + n * 16 + l15];
  __builtin_amdgcn_s_barrier();
  #pragma unroll
  for (int r = 0; r < 4; ++r) {
    float z = 0.f;
    #pragma unroll
    for (int n = 0; n < 8; ++n) z += awacc[n][r] * wv[n];
    z += __shfl_xor(z, 1); z += __shfl_xor(z, 2);
    z += __shfl_xor(z, 4); z += __shfl_xor(z, 8);
    const float zi = 1.f / z;
    const int rr = wband * 16 + hi * 4 + r;
    #pragma unroll
    for (int n = 0; n < 8; ++n) {
      const int cl = n * 16 + l15;
      const int c = cl & 63;
      GP[cl >> 6][rr * 64 + ((((c >> 3) ^ (rr & 7)) << 3) | (c & 7))] =
          f2b(awacc[n][r] * wv[n] * zi);
    }
  }
  asm volatile("s_waitcnt vmcnt(0)" ::: "memory");
  #pragma unroll
  for (int i = 0; i < 4; ++i) {
    const int id = i * 512 + t;
    const int jr = id >> 4;
    const int cc = (id & 15) * 8;
    const int kt2 = jr >> 6, kr = jr & 63;
    #pragma unroll
    for (int j = 0; j < 8; ++j) {
      const int drow = cc + j;
      const int sxz = (((drow & 7) ^ ((drow >> 3) & 7)) << 3);
      Xr[kt2][drow * 64 + (kr ^ sxz)] = xtr[i][j];
    }
  }
  __builtin_amdgcn_s_barrier();
  f32x4 tacc[8];
  #pragma unroll
  for (int n = 0; n < 8; ++n) tacc[n] = (f32x4){0.f, 0.f, 0.f, 0.f};
  __builtin_amdgcn_s_setprio(1);
  #pragma unroll
  for (int kt = 0; kt < 2; ++kt)
    #pragma unroll
    for (int ks = 0; ks < 2; ++ks) {
      const int gck = ((ks * 4 + hi) ^ rsw) * 8;
      bf16x8 a, bb[8];
      a = *(const bf16x8*)&GP[kt][(wband * 16 + l15) * 64 + gck];
      #pragma unroll
      for (int n = 0; n < 8; ++n) {
        const int nr = n * 16 + l15;
        const int sxz = (((nr & 7) ^ ((nr >> 3) & 7)) << 3);
        bb[n] = *(const bf16x8*)&Xr[kt][nr * 64 + ((ks * 32 + hi * 8) ^ sxz)];
      }
      #pragma unroll
      for (int n = 0; n < 8; ++n) tacc[n] = MFMA16(a, bb[n], tacc[n]);
    }
  __builtin_amdgcn_s_setprio(0);
  #pragma unroll
  for (int r = 0; r < 4; ++r) {
    const int row = wband * 16 + hi * 4 + r;
    #pragma unroll
    for (int n = 0; n < 8; ++n) {
      const int col = n * 16 + l15;
      tout[(size_t)b * 16384 + (size_t)row * 128 + col] = f2b(tacc[n][r]);
    }
  }
}

// =======================================================================================
extern "C" void kernel_launch(void* const* d_in, const int* in_sizes, int n_in,
                              void* d_out, int out_size, void* d_ws, size_t ws_size,
                              hipStream_t stream) {
  (void)in_sizes; (void)n_in; (void)out_size; (void)ws_size;
  const float* x     = (const float*)d_in[0];
  const float* wts   = (const float*)d_in[1];
  const float* emb_W = (const float*)d_in[2];
  const float* emb_b = (const float*)d_in[3];
  const float* wq_W  = (const float*)d_in[4];
  const float* wq_b  = (const float*)d_in[5];
  const float* wk_W  = (const float*)d_in[6];
  const float* wk_b  = (const float*)d_in[7];
  const float* wv_W  = (const float*)d_in[8];
  const float* wv_b  = (const float*)d_in[9];
  const float* ipW   = (const float*)d_in[10];
  const float* ipb   = (const float*)d_in[11];
  const float* ln_g  = (const float*)d_in[12];
  const float* ln_b  = (const float*)d_in[13];
  const float* out_W = (const float*)d_in[14];
  const float* out_b = (const float*)d_in[15];

  char* ws = (char*)d_ws;
  size_t off = 0;
  auto alloc = [&](size_t bytes) { void* p = ws + off; off += (bytes + 255) & ~(size_t)255; return p; };
  uint16_t* wqW_bf = (uint16_t*)alloc(524288);
  uint16_t* wkW_bf = (uint16_t*)alloc(524288);
  uint16_t* ip_bf  = (uint16_t*)alloc(1048576);
  uint16_t* owW_bf = (uint16_t*)alloc(131072);     // Wg2 = out_W * ln_g
  uint16_t* Wqc    = (uint16_t*)alloc(524288);     // contiguous Wqc,Wkc,Wvc
  uint16_t* Wkc    = (uint16_t*)alloc(524288);
  uint16_t* Wvc    = (uint16_t*)alloc(524288);
  uint16_t* embW2  = (uint16_t*)alloc(131072);     // contiguous embW2,Wqe,Wke,Wve
  uint16_t* Wqe    = (uint16_t*)alloc(131072);
  uint16_t* Wke    = (uint16_t*)alloc(131072);
  uint16_t* Wve    = (uint16_t*)alloc(131072);
  uint16_t* Wg     = (uint16_t*)alloc(131072);
  float*    vhbuf  = (float*)alloc(2048);
  float*    t1q    = (float*)alloc(2048);
  float*    t1k    = (float*)alloc(2048);
  float*    biasE  = (float*)alloc(2048);
  float*    bqe    = (float*)alloc(2048);
  float*    bke    = (float*)alloc(2048);
  float*    bve    = (float*)alloc(2048);
  float*    uarr   = (float*)alloc(2048);
  float*    varr   = (float*)alloc(2048);
  float*    pad    = (float*)alloc(262144);
  float*    ssum   = (float*)alloc(262144);
  float*    ssq    = (float*)alloc(262144);
  uint16_t* xe     = (uint16_t*)alloc(67108864);
  uint16_t* B1     = (uint16_t*)alloc(67108864);   // t
  uint16_t* B2     = (uint16_t*)alloc(67108864);   // hv

  uint16_t* x_bf = (uint16_t*)d_out + 8388608;     // d_out upper 16 MiB
  uint16_t* tb   = B1;
  uint16_t* hv   = B2;

  const int TB = 256;
  pack_all<<<9600, TB, 0, stream>>>(x, emb_W, wq_W, wk_W, wv_W, ipW, out_W, ln_g,
                                    x_bf, embW2, wqW_bf, wkW_bf, Wvc, ip_bf, owW_bf);
  bias_stage1<<<384, TB, 0, stream>>>(wq_W, wk_W, wv_W, emb_b, wq_b, wk_b, wv_b,
                                      t1q, t1k, bve, pad, biasE, ssum, ssq);
  bias_stage2<<<320, TB, 0, stream>>>(ipW, ipb, t1q, t1k, bqe, bke,
                                      out_W, ln_g, ln_b, out_b, uarr, varr);
  gemm_ab_kernel<<<dim3(4, 4, 2), TB, 0, stream>>>(ip_bf, 512, 262144, wqW_bf, 512, 262144,
                                                   Wqc, 512, 262144, 512);
  gemm_ab_kernel<<<dim3(1, 4, 3), TB, 0, stream>>>(Wqc, 512, 262144, embW2, 128, 0,
                                                   Wqe, 128, 65536, 512);
  gemm_atb_kernel<<<4, TB, 0, stream>>>(Wke, Wqe, bqe, Wg, vhbuf);
  // xe = x @ emb_W^T + emb_b (persistent W; 512-thread blocks, 16 waves/CU)
  gemm_btp_kernel<1, true, false><<<dim3(4, 128, 1), 512, 0, stream>>>(
      x_bf, 0, embW2, 0, biasE, 0, xe, 0, 4, pad, nullptr, nullptr, nullptr);
  // fused attention + PV -> t
  att_fused<<<512, 512, 0, stream>>>(x_bf, Wg, vhbuf, wts, pad, tb);
  // hv = xe + softplus(t @ Wve^T + bve); row stats accumulated via atomics
  gemm_btp_kernel<1, false, true><<<dim3(4, 128, 1), 512, 0, stream>>>(
      tb, 0, Wve, 0, bve, 0, hv, 0, 4, nullptr, xe, ssum, ssq);
  // out = LN-fold: rstd*(hv@Wg2^T - mu*u) + v, f32 -> d_out (512-thread blocks)
  gemm_bt_kernel<float, 0, true><<<dim3(1, 512, 1), 512, 0, stream>>>(
      hv, 0, owW_bf, 0, nullptr, 0, (float*)d_out, 0, 128, 512,
      ssum, ssq, uarr, varr);
}